// Round 2
// baseline (327.459 us; speedup 1.0000x reference)
//
#include <hip/hip_runtime.h>
#include <hip/hip_bf16.h>
#include <math.h>

// Problem constants (HC2MMoE)
#define B_    16384
#define IN_   1024
#define E_    6
#define D_    20
#define EH1_  256
#define EH2_  128
#define EO_   10
#define GH_   64
#define TH_   64

typedef short  s16x8  __attribute__((ext_vector_type(8)));   // 8 bf16 = 4 VGPRs
typedef float  f32x4  __attribute__((ext_vector_type(4)));
typedef float  f32x16 __attribute__((ext_vector_type(16)));

__device__ inline ushort f2bf(float f) {   // RNE fp32 -> bf16 bits
    union { float f; uint32_t u; } v; v.f = f;
    return (ushort)((v.u + 0x7fffu + ((v.u >> 16) & 1u)) >> 16);
}

#define GLOBAL_LDS16(g, l)                                                     \
    __builtin_amdgcn_global_load_lds(                                          \
        (const __attribute__((address_space(1))) void*)(g),                    \
        (__attribute__((address_space(3))) void*)(l), 16, 0, 0)

// ---------------------------------------------------------------------------
// Prep: fused x-convert + 3 weight transposes (flat grid, uniform branch)
// ---------------------------------------------------------------------------
#define CVT_BLKS  (B_ * IN_ / 4 / 256)                       // 16384
#define WT1_TILES ((EH1_ / 32) * (IN_ / 32) * E_)            // 1536
#define WT2_TILES ((EH2_ / 32) * (EH1_ / 32) * E_)           // 192
#define WTG_TILES ((GH_ / 32) * (IN_ / 32) * D_)             // 1280
#define PREP_BLKS (CVT_BLKS + WT1_TILES + WT2_TILES + WTG_TILES)

__global__ __launch_bounds__(256) void k_prep(
        const float* __restrict__ x, ushort* __restrict__ xb,
        const float* __restrict__ Ew1, ushort* __restrict__ W1t,
        const float* __restrict__ Ew2, ushort* __restrict__ W2t,
        const float* __restrict__ Gw1, ushort* __restrict__ G1t) {
    __shared__ float tile[32][33];
    int bid = blockIdx.x;
    const int t = threadIdx.x;

    if (bid < CVT_BLKS) {
        int i = bid * 256 + t;
        float4 v = ((const float4*)x)[i];
        ushort4 o;
        o.x = f2bf(v.x); o.y = f2bf(v.y); o.z = f2bf(v.z); o.w = f2bf(v.w);
        ((ushort4*)xb)[i] = o;
        return;
    }
    bid -= CVT_BLKS;

    const float* W; ushort* Wt; int K, N, z, ky, nx;
    if (bid < WT1_TILES) {
        W = Ew1; Wt = W1t; K = IN_; N = EH1_;
        z = bid / (8 * 32); int r = bid % (8 * 32); ky = r / 8; nx = r % 8;
    } else if (bid < WT1_TILES + WT2_TILES) {
        bid -= WT1_TILES;
        W = Ew2; Wt = W2t; K = EH1_; N = EH2_;
        z = bid / (4 * 8); int r = bid % (4 * 8); ky = r / 4; nx = r % 4;
    } else {
        bid -= WT1_TILES + WT2_TILES;
        W = Gw1; Wt = G1t; K = IN_; N = GH_;
        z = bid / (2 * 32); int r = bid % (2 * 32); ky = r / 2; nx = r % 2;
    }
    const int n0 = nx * 32, k0 = ky * 32;
    const float* We = W + (size_t)z * K * N;
    ushort* Wte = Wt + (size_t)z * K * N;
    const int lx = t & 31, ly = t >> 5;
    #pragma unroll
    for (int r = 0; r < 4; ++r)
        tile[ly + r * 8][lx] = We[(size_t)(k0 + ly + r * 8) * N + n0 + lx];
    __syncthreads();
    #pragma unroll
    for (int r = 0; r < 4; ++r)
        Wte[(size_t)(n0 + ly + r * 8) * K + k0 + lx] = f2bf(tile[lx][ly + r * 8]);
}

// ---------------------------------------------------------------------------
// Fused histogram + prefix (single block, LDS atomics)
// ---------------------------------------------------------------------------
__global__ __launch_bounds__(256) void k_prefix2(
        const int* __restrict__ dom, int* __restrict__ hist,
        int* __restrict__ baseA, int* __restrict__ cursor) {
    __shared__ int h[D_];
    const int t = threadIdx.x;
    if (t < D_) h[t] = 0;
    __syncthreads();
    for (int i = t; i < B_; i += 256) atomicAdd(&h[dom[i]], 1);
    __syncthreads();
    if (t == 0) {
        int s = 0;
        for (int i = 0; i < D_; ++i) {
            baseA[i] = s; cursor[i] = s; hist[i] = h[i]; s += h[i];
        }
    }
}

__global__ void k_scatter(const int* __restrict__ dom, int* __restrict__ cursor,
                          int* __restrict__ perm) {
    int g = blockIdx.x * blockDim.x + threadIdx.x;
    if (g < B_) {
        int pos = atomicAdd(&cursor[dom[g]], 1);
        perm[pos] = g;
    }
}

#define GBK 32
#define H2P 136

// ---------------------------------------------------------------------------
// FUSED expert kernel (R1): h1 = relu(x.W1^T+b1) computed as a 64x256 tile
// (full EH1 panel) kept in LDS in the verified As-panel format (8 panels of
// [64][32], XOR chunk swizzle). Then h2 = relu(h1.W2^T+b2) in-block (K=256),
// then eo = h2.Ew3+b3. Eliminates the 48MB h1 write + 48MB re-read and the
// whole k_l2eo dispatch.
// Verified invariants preserved: staging map (4 lanes cover one row's 64B,
// XOR swizzle), 32x32x16 fragment reads, 1 barrier-pair per 32-K window with
// 8 MFMA/wave/window, acc <= 64 VGPR/lane (R10 lesson).
// LDS: As 4KB + Bs 16KB + h1L 32KB = 52KB -> 3 blocks/CU.
// ---------------------------------------------------------------------------
__global__ __launch_bounds__(256) void k_expert(
        const ushort* __restrict__ xb, const ushort* __restrict__ W1t,
        const float* __restrict__ Eb1, const ushort* __restrict__ W2t,
        const float* __restrict__ Eb2, const float* __restrict__ Ew3,
        const float* __restrict__ Eb3, float* __restrict__ eo) {
    __shared__ __attribute__((aligned(16))) ushort smem[2048 + 8192 + 16384];
    ushort* As  = smem;                 // [64][32]  main-loop A panel
    ushort* Bs  = smem + 2048;          // [256][32] main-loop B panel; L2: W2 panel [128][32]
    ushort* h1L = smem + 2048 + 8192;   // 8 panels x [64][32] (h1, bf16, swizzled)
    ushort* h2L = h1L;                  // epilogue alias: [64][H2P]
    ushort* E3t = h1L + 64 * H2P;       // epilogue alias: [16][H2P]

    const int m0 = blockIdx.x * 64;
    const int e  = blockIdx.y;
    const ushort* W1e = W1t + (size_t)e * EH1_ * IN_;    // [n=256][k=1024]
    const ushort* W2e = W2t + (size_t)e * EH2_ * EH1_;   // [n=128][k=256]

    const int t = threadIdx.x;
    const int wave = t >> 6;
    const int lane = t & 63;

    // staging map (verified): 4 lanes cover one row's contiguous 64B
    const int sA  = t >> 2;                              // 0..63
    const int swA = ((t & 3) ^ ((sA >> 1) & 3)) * 8;

    const int l32  = lane & 31;
    const int ksel = lane >> 5;
    const int quad = lane >> 4;
    const int l16  = lane & 15;

    // ---------------- phase 1: h1 tile 64x256, K=1024 ----------------
    // wave tile: rows rw+[0,32), cols cw+[0,128)
    const int rw = (wave & 1) * 32;
    const int cw = (wave >> 1) * 128;

    const int rowA = rw + l32;
    const int swzA = (rowA >> 1) & 3;
    int rowB[4], swzB[4];
    #pragma unroll
    for (int j = 0; j < 4; ++j) {
        rowB[j] = cw + 32 * j + l32;
        swzB[j] = (rowB[j] >> 1) & 3;
    }

    f32x16 acc1[4] = {};

    for (int k0 = 0; k0 < IN_; k0 += GBK) {
        GLOBAL_LDS16(xb + (size_t)(m0 + sA) * IN_ + k0 + swA, As + wave * 512);
        #pragma unroll
        for (int q = 0; q < 4; ++q)
            GLOBAL_LDS16(W1e + (size_t)(q * 64 + sA) * IN_ + k0 + swA,
                         Bs + q * 2048 + wave * 512);
        __syncthreads();

        #pragma unroll
        for (int h = 0; h < 2; ++h) {
            const int cb = h * 2 + ksel;
            s16x8 af = *(const s16x8*)&As[rowA * GBK + ((cb ^ swzA) * 8)];
            #pragma unroll
            for (int j = 0; j < 4; ++j) {
                s16x8 bf = *(const s16x8*)&Bs[rowB[j] * GBK + ((cb ^ swzB[j]) * 8)];
                acc1[j] = __builtin_amdgcn_mfma_f32_32x32x16_bf16(af, bf, acc1[j], 0, 0, 0);
            }
        }
        __syncthreads();
    }

    // scatter h1 tile into LDS panels (bias+relu+bf16), verified As format:
    // element (row, col): panel col>>5, slot (((col>>3)&3) ^ ((row>>1)&3)), off col&7
    {
        float bi[4];
        #pragma unroll
        for (int j = 0; j < 4; ++j) bi[j] = Eb1[e * EH1_ + cw + 32 * j + l32];
        #pragma unroll
        for (int reg = 0; reg < 16; ++reg) {
            int rowin = (reg & 3) + 8 * (reg >> 2) + 4 * ksel;
            int row = rw + rowin;
            int sz = (row >> 1) & 3;
            #pragma unroll
            for (int j = 0; j < 4; ++j) {
                int p = (cw >> 5) + j;
                int c = (l32 >> 3) & 3;
                float v = fmaxf(acc1[j][reg] + bi[j], 0.f);
                h1L[p * 2048 + row * GBK + ((c ^ sz) * 8) + (l32 & 7)] = f2bf(v);
            }
        }
    }

    // ---------------- phase 2: h2 = relu(h1 . W2^T + b2), 64x128, K=256 ----
    // wave tile: rows rw2+[0,32), cols cw2+[0,64)
    const int rw2 = (wave & 1) * 32;
    const int cw2 = (wave >> 1) * 64;
    const int rowA2 = rw2 + l32;
    const int swzA2 = (rowA2 >> 1) & 3;
    int rowB2[2], swzB2[2];
    #pragma unroll
    for (int j = 0; j < 2; ++j) {
        rowB2[j] = cw2 + 32 * j + l32;
        swzB2[j] = (rowB2[j] >> 1) & 3;
    }

    f32x16 acc2[2] = {};

    for (int kw = 0; kw < EH1_ / GBK; ++kw) {
        #pragma unroll
        for (int q = 0; q < 2; ++q)
            GLOBAL_LDS16(W2e + (size_t)(q * 64 + sA) * EH1_ + kw * GBK + swA,
                         Bs + q * 2048 + wave * 512);
        __syncthreads();   // also covers h1L scatter completion (kw==0)

        #pragma unroll
        for (int h = 0; h < 2; ++h) {
            const int cb = h * 2 + ksel;
            s16x8 af = *(const s16x8*)&h1L[kw * 2048 + rowA2 * GBK + ((cb ^ swzA2) * 8)];
            #pragma unroll
            for (int j = 0; j < 2; ++j) {
                s16x8 bf = *(const s16x8*)&Bs[rowB2[j] * GBK + ((cb ^ swzB2[j]) * 8)];
                acc2[j] = __builtin_amdgcn_mfma_f32_32x32x16_bf16(af, bf, acc2[j], 0, 0, 0);
            }
        }
        __syncthreads();
    }

    // h2 scatter (bias+relu+bf16) into h2L [64][H2P] (aliases h1L, now dead)
    {
        float bi[2];
        #pragma unroll
        for (int j = 0; j < 2; ++j) bi[j] = Eb2[e * EH2_ + cw2 + 32 * j + l32];
        #pragma unroll
        for (int reg = 0; reg < 16; ++reg) {
            int rowin = (reg & 3) + 8 * (reg >> 2) + 4 * ksel;
            int row = rw2 + rowin;
            #pragma unroll
            for (int j = 0; j < 2; ++j)
                h2L[row * H2P + cw2 + 32 * j + l32] =
                    f2bf(fmaxf(acc2[j][reg] + bi[j], 0.f));
        }
    }

    // stage Ew3^T: [16][H2P], cols >= EO_ zero
    for (int i = t; i < 16 * EH2_; i += 256) {
        int col = i >> 7, k = i & 127;
        float v = (col < EO_) ? Ew3[(size_t)e * EH2_ * EO_ + k * EO_ + col] : 0.f;
        E3t[col * H2P + k] = f2bf(v);
    }
    __syncthreads();

    // ---------------- phase 3: eo = h2 . Ew3 + b3 (16x16x32) ----------------
    {
        const int g = wave;           // 4 waves x 16 rows = 64 rows
        f32x4 acc3 = {};
        #pragma unroll
        for (int kc = 0; kc < 4; ++kc) {
            s16x8 a = *(const s16x8*)&h2L[(g * 16 + l16) * H2P + kc * 32 + quad * 8];
            s16x8 b = *(const s16x8*)&E3t[l16 * H2P + kc * 32 + quad * 8];
            acc3 = __builtin_amdgcn_mfma_f32_16x16x32_bf16(a, b, acc3, 0, 0, 0);
        }
        if (l16 < EO_) {
            float b3 = Eb3[e * EO_ + l16];
            #pragma unroll
            for (int r = 0; r < 4; ++r) {
                int row = m0 + g * 16 + quad * 4 + r;
                eo[(size_t)row * (E_ * EO_) + e * EO_ + l16] = acc3[r] + b3;
            }
        }
    }
}

// ---------------------------------------------------------------------------
// Gate (MFMA, fused): per (domain, 64-row tile) block, with bank swizzle.
// ---------------------------------------------------------------------------
__global__ __launch_bounds__(256) void k_gate2(
        const ushort* __restrict__ xb, const ushort* __restrict__ Gw1t,
        const float* __restrict__ Gb1, const float* __restrict__ Gw2,
        const float* __restrict__ Gb2, const int* __restrict__ perm,
        const int* __restrict__ baseA, const int* __restrict__ cntA,
        float* __restrict__ gate) {
    const int d = blockIdx.y;
    const int cnt = cntA[d];
    const int start = blockIdx.x * 64;
    if (start >= cnt) return;
    const int base = baseA[d];

    __shared__ __attribute__((aligned(16))) ushort As[64 * 32];
    __shared__ __attribute__((aligned(16))) ushort Bs[64 * 32];
    __shared__ int    ridx[64];
    __shared__ float  gh[64][GH_ + 1];
    __shared__ float  w2s[GH_ * E_];
    __shared__ float  b2s[E_];
    __shared__ float  lg[64][E_];

    const int t = threadIdx.x;
    const int wave = t >> 6;
    const int lane = t & 63;
    const int quad = lane >> 4;
    const int l16  = lane & 15;
    const int qsw  = (quad ^ ((l16 >> 1) & 3)) * 8;

    if (t < 64) {
        int p = start + t;
        ridx[t] = (p < cnt) ? perm[base + p] : perm[base];  // clamp OOB
    }
    for (int i = t; i < GH_ * E_; i += 256) w2s[i] = Gw2[(size_t)d * GH_ * E_ + i];
    if (t < E_) b2s[t] = Gb2[d * E_ + t];
    __syncthreads();

    const int srow = t >> 2;
    const int sw   = ((t & 3) ^ ((srow >> 1) & 3)) * 8;
    const int myRow = ridx[srow];
    const ushort* aRow = xb + (size_t)myRow * IN_ + sw;
    const ushort* bRow = Gw1t + (size_t)d * GH_ * IN_ + (size_t)srow * IN_ + sw;

    f32x4 acc[4] = {};
    for (int k0 = 0; k0 < IN_; k0 += 32) {
        GLOBAL_LDS16(aRow + k0, As + wave * 512);
        GLOBAL_LDS16(bRow + k0, Bs + wave * 512);
        __syncthreads();

        s16x8 bf = *(const s16x8*)&Bs[(wave * 16 + l16) * 32 + qsw];
        #pragma unroll
        for (int i = 0; i < 4; ++i) {
            s16x8 af = *(const s16x8*)&As[(16 * i + l16) * 32 + qsw];
            acc[i] = __builtin_amdgcn_mfma_f32_16x16x32_bf16(af, bf, acc[i], 0, 0, 0);
        }
        __syncthreads();
    }

    const int hcol = wave * 16 + l16;
    float hb = Gb1[d * GH_ + hcol];
    #pragma unroll
    for (int i = 0; i < 4; ++i)
        #pragma unroll
        for (int r = 0; r < 4; ++r)
            gh[16 * i + quad * 4 + r][hcol] = fmaxf(acc[i][r] + hb, 0.f);
    __syncthreads();

    // layer 2: 64 rows x 6 experts = 384 pairs, strided over 256 threads
    for (int p = t; p < 64 * E_; p += 256) {
        int row = p / E_, e = p - row * E_;
        float s = b2s[e];
        #pragma unroll 8
        for (int h = 0; h < GH_; ++h) s += gh[row][h] * w2s[h * E_ + e];
        lg[row][e] = s;
    }
    __syncthreads();

    if (t < 64 && start + t < cnt) {
        int b = ridx[t];
        float mx = lg[t][0];
        #pragma unroll
        for (int e = 1; e < E_; ++e) mx = fmaxf(mx, lg[t][e]);
        float ex[E_], sum = 0.f;
        #pragma unroll
        for (int e = 0; e < E_; ++e) { ex[e] = expf(lg[t][e] - mx); sum += ex[e]; }
        float inv = 1.f / sum;
        #pragma unroll
        for (int e = 0; e < E_; ++e) gate[(size_t)b * E_ + e] = ex[e] * inv;
    }
}

// ---------------------------------------------------------------------------
// Final: MMoE combine + avg + tower, one wave per sample
// ---------------------------------------------------------------------------
__global__ __launch_bounds__(256) void k_final(
        const float* __restrict__ eo, const float* __restrict__ gate,
        const int* __restrict__ dom,
        const float* __restrict__ Tw1, const float* __restrict__ Tb1,
        const float* __restrict__ Tw2, const float* __restrict__ Tb2,
        float* __restrict__ out) {
    const int wave = threadIdx.x >> 6;
    const int lane = threadIdx.x & 63;
    const int b = blockIdx.x * 4 + wave;
    const int d = dom[b];

    const float* eob = eo + (size_t)b * (E_ * EO_);
    float g[E_];
    #pragma unroll
    for (int e = 0; e < E_; ++e) g[e] = gate[(size_t)b * E_ + e];

    float mmoe[EO_], avg[EO_];
    #pragma unroll
    for (int o = 0; o < EO_; ++o) {
        float m = 0.f, a = 0.f;
        #pragma unroll
        for (int e = 0; e < E_; ++e) {
            float v = eob[e * EO_ + o];
            m += g[e] * v;
            a += v;
        }
        mmoe[o] = m;
        avg[o] = a * (1.0f / E_);
    }

    float acc = Tb1[d * TH_ + lane];
    #pragma unroll
    for (int o = 0; o < EO_; ++o)
        acc += mmoe[o] * Tw1[(size_t)d * EO_ * TH_ + o * TH_ + lane];
    acc = fmaxf(acc, 0.f);

    float s = acc * Tw2[d * TH_ + lane];
    #pragma unroll
    for (int off = 32; off >= 1; off >>= 1) s += __shfl_xor(s, off, 64);

    if (lane == 0)
        out[b] = 1.f / (1.f + expf(-(s + Tb2[d])));
    if (lane < EO_) {
        out[B_ + (size_t)b * EO_ + lane] = avg[lane];
        out[B_ + (size_t)B_ * EO_ + (size_t)b * EO_ + lane] = mmoe[lane];
    }
}

// ---------------------------------------------------------------------------
extern "C" void kernel_launch(void* const* d_in, const int* in_sizes, int n_in,
                              void* d_out, int out_size, void* d_ws, size_t ws_size,
                              hipStream_t stream) {
    const float* x   = (const float*)d_in[0];
    const int*   dom = (const int*)d_in[1];
    const float* Ew1 = (const float*)d_in[2];
    const float* Eb1 = (const float*)d_in[3];
    const float* Ew2 = (const float*)d_in[4];
    const float* Eb2 = (const float*)d_in[5];
    const float* Ew3 = (const float*)d_in[6];
    const float* Eb3 = (const float*)d_in[7];
    const float* Gw1 = (const float*)d_in[8];
    const float* Gb1 = (const float*)d_in[9];
    const float* Gw2 = (const float*)d_in[10];
    const float* Gb2 = (const float*)d_in[11];
    const float* Tw1 = (const float*)d_in[12];
    const float* Tb1 = (const float*)d_in[13];
    const float* Tw2 = (const float*)d_in[14];
    const float* Tb2 = (const float*)d_in[15];
    float* out = (float*)d_out;

    char* ws = (char*)d_ws;
    size_t off = 0;
    auto take = [&](size_t bytes) -> char* {
        char* p = ws + off;
        off = (off + bytes + 255) & ~(size_t)255;
        return p;
    };
    int*    hist    = (int*)take(D_ * 4);
    int*    baseA   = (int*)take(D_ * 4);
    int*    cursor  = (int*)take(D_ * 4);
    int*    perm    = (int*)take(B_ * 4);
    float*  gateBuf = (float*)take((size_t)B_ * E_ * 4);
    float*  eoBuf   = (float*)take((size_t)B_ * E_ * EO_ * 4);
    ushort* xb      = (ushort*)take((size_t)B_ * IN_ * 2);
    ushort* W1t     = (ushort*)take((size_t)E_ * IN_ * EH1_ * 2);
    ushort* W2t     = (ushort*)take((size_t)E_ * EH1_ * EH2_ * 2);
    ushort* G1t     = (ushort*)take((size_t)D_ * IN_ * GH_ * 2);

    // fused conversions (cvt + all weight transposes)
    k_prep<<<dim3(PREP_BLKS), dim3(256), 0, stream>>>(
        x, xb, Ew1, W1t, Ew2, W2t, Gw1, G1t);

    // domain bucketing (hist+prefix fused, then scatter)
    k_prefix2<<<dim3(1), dim3(256), 0, stream>>>(dom, hist, baseA, cursor);
    k_scatter<<<dim3(B_ / 256), dim3(256), 0, stream>>>(dom, cursor, perm);

    // gates (selected domain only, MFMA + fused softmax)
    k_gate2<<<dim3((B_ + 63) / 64, D_), dim3(256), 0, stream>>>(
        xb, G1t, Gb1, Gw2, Gb2, perm, baseA, hist, gateBuf);

    // experts: fully fused L1+L2+L3 (no h1 round-trip)
    k_expert<<<dim3(B_ / 64, E_), dim3(256), 0, stream>>>(
        xb, W1t, Eb1, W2t, Eb2, Ew3, Eb3, eoBuf);

    // combine + towers + outputs
    k_final<<<dim3(B_ / 4), dim3(256), 0, stream>>>(
        eoBuf, gateBuf, dom, Tw1, Tb1, Tw2, Tb2, out);
}

// Round 3
// 256.341 us; speedup vs baseline: 1.2774x; 1.2774x over previous
//
#include <hip/hip_runtime.h>
#include <hip/hip_bf16.h>
#include <math.h>

// Problem constants (HC2MMoE)
#define B_    16384
#define IN_   1024
#define E_    6
#define D_    20
#define EH1_  256
#define EH2_  128
#define EO_   10
#define GH_   64
#define TH_   64

typedef short  s16x8  __attribute__((ext_vector_type(8)));   // 8 bf16 = 4 VGPRs
typedef float  f32x4  __attribute__((ext_vector_type(4)));
typedef float  f32x16 __attribute__((ext_vector_type(16)));

__device__ inline ushort f2bf(float f) {   // RNE fp32 -> bf16 bits
    union { float f; uint32_t u; } v; v.f = f;
    return (ushort)((v.u + 0x7fffu + ((v.u >> 16) & 1u)) >> 16);
}

#define GLOBAL_LDS16(g, l)                                                     \
    __builtin_amdgcn_global_load_lds(                                          \
        (const __attribute__((address_space(1))) void*)(g),                    \
        (__attribute__((address_space(3))) void*)(l), 16, 0, 0)

// ---------------------------------------------------------------------------
// Prep: fused x-convert + 3 weight transposes + domain histogram
// ---------------------------------------------------------------------------
#define CVT_BLKS  (B_ * IN_ / 4 / 256)                       // 16384
#define WT1_TILES ((EH1_ / 32) * (IN_ / 32) * E_)            // 1536
#define WT2_TILES ((EH2_ / 32) * (EH1_ / 32) * E_)           // 192
#define WTG_TILES ((GH_ / 32) * (IN_ / 32) * D_)             // 1280
#define HIST_BLKS (B_ / 256)                                 // 64
#define PREP_BLKS (CVT_BLKS + WT1_TILES + WT2_TILES + WTG_TILES + HIST_BLKS)

__global__ __launch_bounds__(256) void k_prep(
        const float* __restrict__ x, ushort* __restrict__ xb,
        const float* __restrict__ Ew1, ushort* __restrict__ W1t,
        const float* __restrict__ Ew2, ushort* __restrict__ W2t,
        const float* __restrict__ Gw1, ushort* __restrict__ G1t,
        const int* __restrict__ dom, int* __restrict__ hist) {
    __shared__ float tile[32][33];
    __shared__ int hcnt[D_];
    int bid = blockIdx.x;
    const int t = threadIdx.x;

    if (bid < CVT_BLKS) {
        int i = bid * 256 + t;
        float4 v = ((const float4*)x)[i];
        ushort4 o;
        o.x = f2bf(v.x); o.y = f2bf(v.y); o.z = f2bf(v.z); o.w = f2bf(v.w);
        ((ushort4*)xb)[i] = o;
        return;
    }
    bid -= CVT_BLKS;

    const float* W; ushort* Wt; int K, N, z, ky, nx;
    if (bid < WT1_TILES) {
        W = Ew1; Wt = W1t; K = IN_; N = EH1_;
        z = bid / (8 * 32); int r = bid % (8 * 32); ky = r / 8; nx = r % 8;
    } else if (bid < WT1_TILES + WT2_TILES) {
        bid -= WT1_TILES;
        W = Ew2; Wt = W2t; K = EH1_; N = EH2_;
        z = bid / (4 * 8); int r = bid % (4 * 8); ky = r / 4; nx = r % 4;
    } else if (bid < WT1_TILES + WT2_TILES + WTG_TILES) {
        bid -= WT1_TILES + WT2_TILES;
        W = Gw1; Wt = G1t; K = IN_; N = GH_;
        z = bid / (2 * 32); int r = bid % (2 * 32); ky = r / 2; nx = r % 2;
    } else {
        // histogram blocks: 256 samples each, LDS counts -> 20 global atomics
        int base = (bid - (WT1_TILES + WT2_TILES + WTG_TILES)) * 256;
        if (t < D_) hcnt[t] = 0;
        __syncthreads();
        atomicAdd(&hcnt[dom[base + t]], 1);
        __syncthreads();
        if (t < D_ && hcnt[t] > 0) atomicAdd(&hist[t], hcnt[t]);
        return;
    }
    const int n0 = nx * 32, k0 = ky * 32;
    const float* We = W + (size_t)z * K * N;
    ushort* Wte = Wt + (size_t)z * K * N;
    const int lx = t & 31, ly = t >> 5;
    #pragma unroll
    for (int r = 0; r < 4; ++r)
        tile[ly + r * 8][lx] = We[(size_t)(k0 + ly + r * 8) * N + n0 + lx];
    __syncthreads();
    #pragma unroll
    for (int r = 0; r < 4; ++r)
        Wte[(size_t)(n0 + ly + r * 8) * K + k0 + lx] = f2bf(tile[lx][ly + r * 8]);
}

// ---------------------------------------------------------------------------
// Chunked scatter: per-block LDS counts -> one global atomic per (block,
// domain) chunk reservation -> in-block rank. Replaces 16384 same-address
// device atomics with 1280. Bucket-internal order is free (gate is
// order-invariant).
// ---------------------------------------------------------------------------
__global__ __launch_bounds__(256) void k_scatter2(
        const int* __restrict__ dom, const int* __restrict__ hist,
        int* __restrict__ cursor0, int* __restrict__ perm) {
    __shared__ int lcnt[D_];
    __shared__ int lbase[D_];
    const int t = threadIdx.x;
    const int g = blockIdx.x * 256 + t;
    if (t < D_) lcnt[t] = 0;
    __syncthreads();
    const int d = dom[g];
    atomicAdd(&lcnt[d], 1);
    __syncthreads();
    if (t < D_) {
        int base = 0;
        #pragma unroll
        for (int i = 0; i < D_; ++i) if (i < t) base += hist[i];
        lbase[t] = base + atomicAdd(&cursor0[t], lcnt[t]);
    }
    __syncthreads();
    if (t < D_) lcnt[t] = 0;
    __syncthreads();
    int r = atomicAdd(&lcnt[d], 1);
    perm[lbase[d] + r] = g;
}

#define GBK 32
#define H2P 136

// ---------------------------------------------------------------------------
// MERGED expert+gate kernel. blockIdx.y < E_: fused expert L1+L2+L3 (R2
// verified path, byte-identical). blockIdx.y >= E_: gate for domain y-E_
// (R0-verified gate2, base/cnt computed locally from hist).
// ---------------------------------------------------------------------------
__global__ __launch_bounds__(256) void k_eg(
        const ushort* __restrict__ xb, const ushort* __restrict__ W1t,
        const float* __restrict__ Eb1, const ushort* __restrict__ W2t,
        const float* __restrict__ Eb2, const float* __restrict__ Ew3,
        const float* __restrict__ Eb3, float* __restrict__ eo,
        const ushort* __restrict__ Gw1t, const float* __restrict__ Gb1,
        const float* __restrict__ Gw2, const float* __restrict__ Gb2,
        const int* __restrict__ perm, const int* __restrict__ hist,
        float* __restrict__ gate) {
    __shared__ __attribute__((aligned(16))) ushort smem[2048 + 8192 + 16384];

    const int t = threadIdx.x;
    const int wave = t >> 6;
    const int lane = t & 63;
    const int l32  = lane & 31;
    const int ksel = lane >> 5;
    const int quad = lane >> 4;
    const int l16  = lane & 15;

    // staging map (verified): 4 lanes cover one row's contiguous 64B
    const int sA  = t >> 2;                              // 0..63
    const int swA = ((t & 3) ^ ((sA >> 1) & 3)) * 8;

    if (blockIdx.y < E_) {
        // ================= EXPERT branch (unchanged from R2) ==============
        ushort* As  = smem;                 // [64][32]
        ushort* Bs  = smem + 2048;          // [256][32]
        ushort* h1L = smem + 2048 + 8192;   // 8 panels x [64][32]
        ushort* h2L = h1L;                  // alias: [64][H2P]
        ushort* E3t = h1L + 64 * H2P;       // alias: [16][H2P]

        const int m0 = blockIdx.x * 64;
        const int e  = blockIdx.y;
        const ushort* W1e = W1t + (size_t)e * EH1_ * IN_;
        const ushort* W2e = W2t + (size_t)e * EH2_ * EH1_;

        const int rw = (wave & 1) * 32;
        const int cw = (wave >> 1) * 128;

        const int rowA = rw + l32;
        const int swzA = (rowA >> 1) & 3;
        int rowB[4], swzB[4];
        #pragma unroll
        for (int j = 0; j < 4; ++j) {
            rowB[j] = cw + 32 * j + l32;
            swzB[j] = (rowB[j] >> 1) & 3;
        }

        f32x16 acc1[4] = {};

        for (int k0 = 0; k0 < IN_; k0 += GBK) {
            GLOBAL_LDS16(xb + (size_t)(m0 + sA) * IN_ + k0 + swA, As + wave * 512);
            #pragma unroll
            for (int q = 0; q < 4; ++q)
                GLOBAL_LDS16(W1e + (size_t)(q * 64 + sA) * IN_ + k0 + swA,
                             Bs + q * 2048 + wave * 512);
            __syncthreads();

            #pragma unroll
            for (int h = 0; h < 2; ++h) {
                const int cb = h * 2 + ksel;
                s16x8 af = *(const s16x8*)&As[rowA * GBK + ((cb ^ swzA) * 8)];
                #pragma unroll
                for (int j = 0; j < 4; ++j) {
                    s16x8 bf = *(const s16x8*)&Bs[rowB[j] * GBK + ((cb ^ swzB[j]) * 8)];
                    acc1[j] = __builtin_amdgcn_mfma_f32_32x32x16_bf16(af, bf, acc1[j], 0, 0, 0);
                }
            }
            __syncthreads();
        }

        {
            float bi[4];
            #pragma unroll
            for (int j = 0; j < 4; ++j) bi[j] = Eb1[e * EH1_ + cw + 32 * j + l32];
            #pragma unroll
            for (int reg = 0; reg < 16; ++reg) {
                int rowin = (reg & 3) + 8 * (reg >> 2) + 4 * ksel;
                int row = rw + rowin;
                int sz = (row >> 1) & 3;
                #pragma unroll
                for (int j = 0; j < 4; ++j) {
                    int p = (cw >> 5) + j;
                    int c = (l32 >> 3) & 3;
                    float v = fmaxf(acc1[j][reg] + bi[j], 0.f);
                    h1L[p * 2048 + row * GBK + ((c ^ sz) * 8) + (l32 & 7)] = f2bf(v);
                }
            }
        }

        const int rw2 = (wave & 1) * 32;
        const int cw2 = (wave >> 1) * 64;
        const int rowA2 = rw2 + l32;
        const int swzA2 = (rowA2 >> 1) & 3;
        int rowB2[2], swzB2[2];
        #pragma unroll
        for (int j = 0; j < 2; ++j) {
            rowB2[j] = cw2 + 32 * j + l32;
            swzB2[j] = (rowB2[j] >> 1) & 3;
        }

        f32x16 acc2[2] = {};

        for (int kw = 0; kw < EH1_ / GBK; ++kw) {
            #pragma unroll
            for (int q = 0; q < 2; ++q)
                GLOBAL_LDS16(W2e + (size_t)(q * 64 + sA) * EH1_ + kw * GBK + swA,
                             Bs + q * 2048 + wave * 512);
            __syncthreads();

            #pragma unroll
            for (int h = 0; h < 2; ++h) {
                const int cb = h * 2 + ksel;
                s16x8 af = *(const s16x8*)&h1L[kw * 2048 + rowA2 * GBK + ((cb ^ swzA2) * 8)];
                #pragma unroll
                for (int j = 0; j < 2; ++j) {
                    s16x8 bf = *(const s16x8*)&Bs[rowB2[j] * GBK + ((cb ^ swzB2[j]) * 8)];
                    acc2[j] = __builtin_amdgcn_mfma_f32_32x32x16_bf16(af, bf, acc2[j], 0, 0, 0);
                }
            }
            __syncthreads();
        }

        {
            float bi[2];
            #pragma unroll
            for (int j = 0; j < 2; ++j) bi[j] = Eb2[e * EH2_ + cw2 + 32 * j + l32];
            #pragma unroll
            for (int reg = 0; reg < 16; ++reg) {
                int rowin = (reg & 3) + 8 * (reg >> 2) + 4 * ksel;
                int row = rw2 + rowin;
                #pragma unroll
                for (int j = 0; j < 2; ++j)
                    h2L[row * H2P + cw2 + 32 * j + l32] =
                        f2bf(fmaxf(acc2[j][reg] + bi[j], 0.f));
            }
        }

        for (int i = t; i < 16 * EH2_; i += 256) {
            int col = i >> 7, k = i & 127;
            float v = (col < EO_) ? Ew3[(size_t)e * EH2_ * EO_ + k * EO_ + col] : 0.f;
            E3t[col * H2P + k] = f2bf(v);
        }
        __syncthreads();

        {
            const int g = wave;
            f32x4 acc3 = {};
            #pragma unroll
            for (int kc = 0; kc < 4; ++kc) {
                s16x8 a = *(const s16x8*)&h2L[(g * 16 + l16) * H2P + kc * 32 + quad * 8];
                s16x8 b = *(const s16x8*)&E3t[l16 * H2P + kc * 32 + quad * 8];
                acc3 = __builtin_amdgcn_mfma_f32_16x16x32_bf16(a, b, acc3, 0, 0, 0);
            }
            if (l16 < EO_) {
                float b3 = Eb3[e * EO_ + l16];
                #pragma unroll
                for (int r = 0; r < 4; ++r) {
                    int row = m0 + g * 16 + quad * 4 + r;
                    eo[(size_t)row * (E_ * EO_) + e * EO_ + l16] = acc3[r] + b3;
                }
            }
        }
        return;
    }

    // ===================== GATE branch (domain d) =========================
    {
        const int d = blockIdx.y - E_;

        // carve gate LDS out of smem (byte offsets; all within 53248)
        ushort* gAs  = smem;                                   // 4096 B
        ushort* gBs  = smem + 2048;                            // 4096 B
        int*    ridx = (int*)(smem + 4096);                    // 256 B @8192
        float (*gh)[GH_ + 1] = (float(*)[GH_ + 1])(smem + 4224);   // 16640 B @8448
        float*  w2s  = (float*)(smem + 12544);                 // 1536 B @25088
        float*  b2s  = (float*)(smem + 13312);                 // 24 B @26624
        float (*lg)[E_] = (float(*)[E_])(smem + 13324);        // 1536 B @26648
        int*    sbc  = (int*)(smem + 14092);                   // 8 B @28184

        if (t == 0) {
            int s = 0;
            #pragma unroll
            for (int i = 0; i < D_; ++i) if (i < d) s += hist[i];
            sbc[0] = s; sbc[1] = hist[d];
        }
        __syncthreads();
        const int base = sbc[0], cnt = sbc[1];
        const int start = blockIdx.x * 64;
        if (start >= cnt) return;

        const int qsw = (quad ^ ((l16 >> 1) & 3)) * 8;

        if (t < 64) {
            int p = start + t;
            ridx[t] = (p < cnt) ? perm[base + p] : perm[base];  // clamp OOB
        }
        for (int i = t; i < GH_ * E_; i += 256) w2s[i] = Gw2[(size_t)d * GH_ * E_ + i];
        if (t < E_) b2s[t] = Gb2[d * E_ + t];
        __syncthreads();

        const int srow = t >> 2;
        const int sw   = ((t & 3) ^ ((srow >> 1) & 3)) * 8;
        const int myRow = ridx[srow];
        const ushort* aRow = xb + (size_t)myRow * IN_ + sw;
        const ushort* bRow = Gw1t + (size_t)d * GH_ * IN_ + (size_t)srow * IN_ + sw;

        f32x4 acc[4] = {};
        for (int k0 = 0; k0 < IN_; k0 += 32) {
            GLOBAL_LDS16(aRow + k0, gAs + wave * 512);
            GLOBAL_LDS16(bRow + k0, gBs + wave * 512);
            __syncthreads();

            s16x8 bf = *(const s16x8*)&gBs[(wave * 16 + l16) * 32 + qsw];
            #pragma unroll
            for (int i = 0; i < 4; ++i) {
                s16x8 af = *(const s16x8*)&gAs[(16 * i + l16) * 32 + qsw];
                acc[i] = __builtin_amdgcn_mfma_f32_16x16x32_bf16(af, bf, acc[i], 0, 0, 0);
            }
            __syncthreads();
        }

        const int hcol = wave * 16 + l16;
        float hb = Gb1[d * GH_ + hcol];
        #pragma unroll
        for (int i = 0; i < 4; ++i)
            #pragma unroll
            for (int r = 0; r < 4; ++r)
                gh[16 * i + quad * 4 + r][hcol] = fmaxf(acc[i][r] + hb, 0.f);
        __syncthreads();

        for (int p = t; p < 64 * E_; p += 256) {
            int row = p / E_, e = p - row * E_;
            float s = b2s[e];
            #pragma unroll 8
            for (int h = 0; h < GH_; ++h) s += gh[row][h] * w2s[h * E_ + e];
            lg[row][e] = s;
        }
        __syncthreads();

        if (t < 64 && start + t < cnt) {
            int b = ridx[t];
            float mx = lg[t][0];
            #pragma unroll
            for (int e = 1; e < E_; ++e) mx = fmaxf(mx, lg[t][e]);
            float ex[E_], sum = 0.f;
            #pragma unroll
            for (int e = 0; e < E_; ++e) { ex[e] = expf(lg[t][e] - mx); sum += ex[e]; }
            float inv = 1.f / sum;
            #pragma unroll
            for (int e = 0; e < E_; ++e) gate[(size_t)b * E_ + e] = ex[e] * inv;
        }
    }
}

// ---------------------------------------------------------------------------
// Final: MMoE combine + avg + tower, one wave per sample
// ---------------------------------------------------------------------------
__global__ __launch_bounds__(256) void k_final(
        const float* __restrict__ eo, const float* __restrict__ gate,
        const int* __restrict__ dom,
        const float* __restrict__ Tw1, const float* __restrict__ Tb1,
        const float* __restrict__ Tw2, const float* __restrict__ Tb2,
        float* __restrict__ out) {
    const int wave = threadIdx.x >> 6;
    const int lane = threadIdx.x & 63;
    const int b = blockIdx.x * 4 + wave;
    const int d = dom[b];

    const float* eob = eo + (size_t)b * (E_ * EO_);
    float g[E_];
    #pragma unroll
    for (int e = 0; e < E_; ++e) g[e] = gate[(size_t)b * E_ + e];

    float mmoe[EO_], avg[EO_];
    #pragma unroll
    for (int o = 0; o < EO_; ++o) {
        float m = 0.f, a = 0.f;
        #pragma unroll
        for (int e = 0; e < E_; ++e) {
            float v = eob[e * EO_ + o];
            m += g[e] * v;
            a += v;
        }
        mmoe[o] = m;
        avg[o] = a * (1.0f / E_);
    }

    float acc = Tb1[d * TH_ + lane];
    #pragma unroll
    for (int o = 0; o < EO_; ++o)
        acc += mmoe[o] * Tw1[(size_t)d * EO_ * TH_ + o * TH_ + lane];
    acc = fmaxf(acc, 0.f);

    float s = acc * Tw2[d * TH_ + lane];
    #pragma unroll
    for (int off = 32; off >= 1; off >>= 1) s += __shfl_xor(s, off, 64);

    if (lane == 0)
        out[b] = 1.f / (1.f + expf(-(s + Tb2[d])));
    if (lane < EO_) {
        out[B_ + (size_t)b * EO_ + lane] = avg[lane];
        out[B_ + (size_t)B_ * EO_ + (size_t)b * EO_ + lane] = mmoe[lane];
    }
}

// ---------------------------------------------------------------------------
extern "C" void kernel_launch(void* const* d_in, const int* in_sizes, int n_in,
                              void* d_out, int out_size, void* d_ws, size_t ws_size,
                              hipStream_t stream) {
    const float* x   = (const float*)d_in[0];
    const int*   dom = (const int*)d_in[1];
    const float* Ew1 = (const float*)d_in[2];
    const float* Eb1 = (const float*)d_in[3];
    const float* Ew2 = (const float*)d_in[4];
    const float* Eb2 = (const float*)d_in[5];
    const float* Ew3 = (const float*)d_in[6];
    const float* Eb3 = (const float*)d_in[7];
    const float* Gw1 = (const float*)d_in[8];
    const float* Gb1 = (const float*)d_in[9];
    const float* Gw2 = (const float*)d_in[10];
    const float* Gb2 = (const float*)d_in[11];
    const float* Tw1 = (const float*)d_in[12];
    const float* Tb1 = (const float*)d_in[13];
    const float* Tw2 = (const float*)d_in[14];
    const float* Tb2 = (const float*)d_in[15];
    float* out = (float*)d_out;

    char* ws = (char*)d_ws;
    size_t off = 0;
    auto take = [&](size_t bytes) -> char* {
        char* p = ws + off;
        off = (off + bytes + 255) & ~(size_t)255;
        return p;
    };
    int*    hist    = (int*)take(D_ * 4);
    int*    cursor0 = (int*)take(D_ * 4);
    int*    perm    = (int*)take(B_ * 4);
    float*  gateBuf = (float*)take((size_t)B_ * E_ * 4);
    float*  eoBuf   = (float*)take((size_t)B_ * E_ * EO_ * 4);
    ushort* xb      = (ushort*)take((size_t)B_ * IN_ * 2);
    ushort* W1t     = (ushort*)take((size_t)E_ * IN_ * EH1_ * 2);
    ushort* W2t     = (ushort*)take((size_t)E_ * EH1_ * EH2_ * 2);
    ushort* G1t     = (ushort*)take((size_t)D_ * IN_ * GH_ * 2);

    // zero hist + cursor0 (adjacent takes, one memset covers both ranges)
    hipMemsetAsync(hist, 0, ((char*)perm - (char*)hist), stream);

    // fused conversions (cvt + weight transposes + histogram)
    k_prep<<<dim3(PREP_BLKS), dim3(256), 0, stream>>>(
        x, xb, Ew1, W1t, Ew2, W2t, Gw1, G1t, dom, hist);

    // chunked scatter (prefix computed in-block from hist)
    k_scatter2<<<dim3(B_ / 256), dim3(256), 0, stream>>>(dom, hist, cursor0, perm);

    // merged: experts (y<6, fused L1+L2+L3) + gates (y>=6)
    k_eg<<<dim3(B_ / 64, E_ + D_), dim3(256), 0, stream>>>(
        xb, W1t, Eb1, W2t, Eb2, Ew3, Eb3, eoBuf,
        G1t, Gb1, Gw2, Gb2, perm, hist, gateBuf);

    // combine + towers + outputs
    k_final<<<dim3(B_ / 4), dim3(256), 0, stream>>>(
        eoBuf, gateBuf, dom, Tw1, Tb1, Tw2, Tb2, out);
}

// Round 4
// 256.135 us; speedup vs baseline: 1.2785x; 1.0008x over previous
//
#include <hip/hip_runtime.h>
#include <hip/hip_bf16.h>
#include <math.h>

// Problem constants (HC2MMoE)
#define B_    16384
#define IN_   1024
#define E_    6
#define D_    20
#define EH1_  256
#define EH2_  128
#define EO_   10
#define GH_   64
#define TH_   64

typedef short  s16x8  __attribute__((ext_vector_type(8)));   // 8 bf16 = 4 VGPRs
typedef float  f32x4  __attribute__((ext_vector_type(4)));
typedef float  f32x16 __attribute__((ext_vector_type(16)));

__device__ inline ushort f2bf(float f) {   // RNE fp32 -> bf16 bits
    union { float f; uint32_t u; } v; v.f = f;
    return (ushort)((v.u + 0x7fffu + ((v.u >> 16) & 1u)) >> 16);
}

#define GLOBAL_LDS16(g, l)                                                     \
    __builtin_amdgcn_global_load_lds(                                          \
        (const __attribute__((address_space(1))) void*)(g),                    \
        (__attribute__((address_space(3))) void*)(l), 16, 0, 0)

// ---------------------------------------------------------------------------
// Prep: fused x-convert (grid-strided) + 3 weight transposes + histogram
// ---------------------------------------------------------------------------
#define CVT_BLKS  2048
#define CVT_ITERS (B_ * IN_ / 4 / 256 / CVT_BLKS)            // 8
#define WT1_TILES ((EH1_ / 32) * (IN_ / 32) * E_)            // 1536
#define WT2_TILES ((EH2_ / 32) * (EH1_ / 32) * E_)           // 192
#define WTG_TILES ((GH_ / 32) * (IN_ / 32) * D_)             // 1280
#define HIST_BLKS (B_ / 256)                                 // 64
#define PREP_BLKS (CVT_BLKS + WT1_TILES + WT2_TILES + WTG_TILES + HIST_BLKS)

__global__ __launch_bounds__(256) void k_prep(
        const float* __restrict__ x, ushort* __restrict__ xb,
        const float* __restrict__ Ew1, ushort* __restrict__ W1t,
        const float* __restrict__ Ew2, ushort* __restrict__ W2t,
        const float* __restrict__ Gw1, ushort* __restrict__ G1t,
        const int* __restrict__ dom, int* __restrict__ hist) {
    __shared__ float tile[32][33];
    __shared__ int hcnt[D_];
    int bid = blockIdx.x;
    const int t = threadIdx.x;

    if (bid < CVT_BLKS) {
        int i = bid * 256 + t;
        #pragma unroll
        for (int it = 0; it < CVT_ITERS; ++it, i += CVT_BLKS * 256) {
            float4 v = ((const float4*)x)[i];
            ushort4 o;
            o.x = f2bf(v.x); o.y = f2bf(v.y); o.z = f2bf(v.z); o.w = f2bf(v.w);
            ((ushort4*)xb)[i] = o;
        }
        return;
    }
    bid -= CVT_BLKS;

    const float* W; ushort* Wt; int K, N, z, ky, nx;
    if (bid < WT1_TILES) {
        W = Ew1; Wt = W1t; K = IN_; N = EH1_;
        z = bid / (8 * 32); int r = bid % (8 * 32); ky = r / 8; nx = r % 8;
    } else if (bid < WT1_TILES + WT2_TILES) {
        bid -= WT1_TILES;
        W = Ew2; Wt = W2t; K = EH1_; N = EH2_;
        z = bid / (4 * 8); int r = bid % (4 * 8); ky = r / 4; nx = r % 4;
    } else if (bid < WT1_TILES + WT2_TILES + WTG_TILES) {
        bid -= WT1_TILES + WT2_TILES;
        W = Gw1; Wt = G1t; K = IN_; N = GH_;
        z = bid / (2 * 32); int r = bid % (2 * 32); ky = r / 2; nx = r % 2;
    } else {
        // histogram blocks: 256 samples each, LDS counts -> 20 global atomics
        int base = (bid - (WT1_TILES + WT2_TILES + WTG_TILES)) * 256;
        if (t < D_) hcnt[t] = 0;
        __syncthreads();
        atomicAdd(&hcnt[dom[base + t]], 1);
        __syncthreads();
        if (t < D_ && hcnt[t] > 0) atomicAdd(&hist[t], hcnt[t]);
        return;
    }
    const int n0 = nx * 32, k0 = ky * 32;
    const float* We = W + (size_t)z * K * N;
    ushort* Wte = Wt + (size_t)z * K * N;
    const int lx = t & 31, ly = t >> 5;
    #pragma unroll
    for (int r = 0; r < 4; ++r)
        tile[ly + r * 8][lx] = We[(size_t)(k0 + ly + r * 8) * N + n0 + lx];
    __syncthreads();
    #pragma unroll
    for (int r = 0; r < 4; ++r)
        Wte[(size_t)(n0 + ly + r * 8) * K + k0 + lx] = f2bf(tile[lx][ly + r * 8]);
}

// ---------------------------------------------------------------------------
// Chunked scatter: per-block LDS counts -> one global atomic per (block,
// domain). Block 0 additionally builds the dense gate-tile table:
// gtab[i] = (domain << 16) | tileIdx, gbase[d] = bucket base (prefix).
// ---------------------------------------------------------------------------
__global__ __launch_bounds__(256) void k_scatter2(
        const int* __restrict__ dom, const int* __restrict__ hist,
        int* __restrict__ cursor0, int* __restrict__ perm,
        int* __restrict__ gbase, int* __restrict__ gtab,
        int* __restrict__ ngt) {
    __shared__ int lcnt[D_];
    __shared__ int lbase[D_];
    const int t = threadIdx.x;
    const int g = blockIdx.x * 256 + t;
    if (blockIdx.x == 0 && t == 0) {
        int s = 0, n = 0;
        for (int d = 0; d < D_; ++d) {
            gbase[d] = s;
            int c = hist[d];
            int nt = (c + 63) >> 6;
            for (int tt = 0; tt < nt; ++tt) gtab[n++] = (d << 16) | tt;
            s += c;
        }
        ngt[0] = n;
    }
    if (t < D_) lcnt[t] = 0;
    __syncthreads();
    const int d = dom[g];
    atomicAdd(&lcnt[d], 1);
    __syncthreads();
    if (t < D_) {
        int base = 0;
        #pragma unroll
        for (int i = 0; i < D_; ++i) if (i < t) base += hist[i];
        lbase[t] = base + atomicAdd(&cursor0[t], lcnt[t]);
    }
    __syncthreads();
    if (t < D_) lcnt[t] = 0;
    __syncthreads();
    int r = atomicAdd(&lcnt[d], 1);
    perm[lbase[d] + r] = g;
}

#define GBK 32
#define H2P 136
#define GY_  (E_ + 2)          // 6 expert slices + 2 gate-table slices

// ---------------------------------------------------------------------------
// MERGED expert+gate kernel. blockIdx.y < E_: fused expert L1+L2+L3 (R2
// verified path, byte-identical). blockIdx.y >= E_: gate tile from dense
// table (no empty per-domain slices).
// ---------------------------------------------------------------------------
__global__ __launch_bounds__(256) void k_eg(
        const ushort* __restrict__ xb, const ushort* __restrict__ W1t,
        const float* __restrict__ Eb1, const ushort* __restrict__ W2t,
        const float* __restrict__ Eb2, const float* __restrict__ Ew3,
        const float* __restrict__ Eb3, float* __restrict__ eo,
        const ushort* __restrict__ Gw1t, const float* __restrict__ Gb1,
        const float* __restrict__ Gw2, const float* __restrict__ Gb2,
        const int* __restrict__ perm, const int* __restrict__ hist,
        const int* __restrict__ gbase, const int* __restrict__ gtab,
        const int* __restrict__ ngt, float* __restrict__ gate) {
    __shared__ __attribute__((aligned(16))) ushort smem[2048 + 8192 + 16384];

    const int t = threadIdx.x;
    const int wave = t >> 6;
    const int lane = t & 63;
    const int l32  = lane & 31;
    const int ksel = lane >> 5;
    const int quad = lane >> 4;
    const int l16  = lane & 15;

    // staging map (verified): 4 lanes cover one row's contiguous 64B
    const int sA  = t >> 2;                              // 0..63
    const int swA = ((t & 3) ^ ((sA >> 1) & 3)) * 8;

    if (blockIdx.y < E_) {
        // ================= EXPERT branch (unchanged from R2) ==============
        ushort* As  = smem;                 // [64][32]
        ushort* Bs  = smem + 2048;          // [256][32]
        ushort* h1L = smem + 2048 + 8192;   // 8 panels x [64][32]
        ushort* h2L = h1L;                  // alias: [64][H2P]
        ushort* E3t = h1L + 64 * H2P;       // alias: [16][H2P]

        const int m0 = blockIdx.x * 64;
        const int e  = blockIdx.y;
        const ushort* W1e = W1t + (size_t)e * EH1_ * IN_;
        const ushort* W2e = W2t + (size_t)e * EH2_ * EH1_;

        const int rw = (wave & 1) * 32;
        const int cw = (wave >> 1) * 128;

        const int rowA = rw + l32;
        const int swzA = (rowA >> 1) & 3;
        int rowB[4], swzB[4];
        #pragma unroll
        for (int j = 0; j < 4; ++j) {
            rowB[j] = cw + 32 * j + l32;
            swzB[j] = (rowB[j] >> 1) & 3;
        }

        f32x16 acc1[4] = {};

        for (int k0 = 0; k0 < IN_; k0 += GBK) {
            GLOBAL_LDS16(xb + (size_t)(m0 + sA) * IN_ + k0 + swA, As + wave * 512);
            #pragma unroll
            for (int q = 0; q < 4; ++q)
                GLOBAL_LDS16(W1e + (size_t)(q * 64 + sA) * IN_ + k0 + swA,
                             Bs + q * 2048 + wave * 512);
            __syncthreads();

            #pragma unroll
            for (int h = 0; h < 2; ++h) {
                const int cb = h * 2 + ksel;
                s16x8 af = *(const s16x8*)&As[rowA * GBK + ((cb ^ swzA) * 8)];
                #pragma unroll
                for (int j = 0; j < 4; ++j) {
                    s16x8 bf = *(const s16x8*)&Bs[rowB[j] * GBK + ((cb ^ swzB[j]) * 8)];
                    acc1[j] = __builtin_amdgcn_mfma_f32_32x32x16_bf16(af, bf, acc1[j], 0, 0, 0);
                }
            }
            __syncthreads();
        }

        {
            float bi[4];
            #pragma unroll
            for (int j = 0; j < 4; ++j) bi[j] = Eb1[e * EH1_ + cw + 32 * j + l32];
            #pragma unroll
            for (int reg = 0; reg < 16; ++reg) {
                int rowin = (reg & 3) + 8 * (reg >> 2) + 4 * ksel;
                int row = rw + rowin;
                int sz = (row >> 1) & 3;
                #pragma unroll
                for (int j = 0; j < 4; ++j) {
                    int p = (cw >> 5) + j;
                    int c = (l32 >> 3) & 3;
                    float v = fmaxf(acc1[j][reg] + bi[j], 0.f);
                    h1L[p * 2048 + row * GBK + ((c ^ sz) * 8) + (l32 & 7)] = f2bf(v);
                }
            }
        }

        const int rw2 = (wave & 1) * 32;
        const int cw2 = (wave >> 1) * 64;
        const int rowA2 = rw2 + l32;
        const int swzA2 = (rowA2 >> 1) & 3;
        int rowB2[2], swzB2[2];
        #pragma unroll
        for (int j = 0; j < 2; ++j) {
            rowB2[j] = cw2 + 32 * j + l32;
            swzB2[j] = (rowB2[j] >> 1) & 3;
        }

        f32x16 acc2[2] = {};

        for (int kw = 0; kw < EH1_ / GBK; ++kw) {
            #pragma unroll
            for (int q = 0; q < 2; ++q)
                GLOBAL_LDS16(W2e + (size_t)(q * 64 + sA) * EH1_ + kw * GBK + swA,
                             Bs + q * 2048 + wave * 512);
            __syncthreads();

            #pragma unroll
            for (int h = 0; h < 2; ++h) {
                const int cb = h * 2 + ksel;
                s16x8 af = *(const s16x8*)&h1L[kw * 2048 + rowA2 * GBK + ((cb ^ swzA2) * 8)];
                #pragma unroll
                for (int j = 0; j < 2; ++j) {
                    s16x8 bf = *(const s16x8*)&Bs[rowB2[j] * GBK + ((cb ^ swzB2[j]) * 8)];
                    acc2[j] = __builtin_amdgcn_mfma_f32_32x32x16_bf16(af, bf, acc2[j], 0, 0, 0);
                }
            }
            __syncthreads();
        }

        {
            float bi[2];
            #pragma unroll
            for (int j = 0; j < 2; ++j) bi[j] = Eb2[e * EH2_ + cw2 + 32 * j + l32];
            #pragma unroll
            for (int reg = 0; reg < 16; ++reg) {
                int rowin = (reg & 3) + 8 * (reg >> 2) + 4 * ksel;
                int row = rw2 + rowin;
                #pragma unroll
                for (int j = 0; j < 2; ++j)
                    h2L[row * H2P + cw2 + 32 * j + l32] =
                        f2bf(fmaxf(acc2[j][reg] + bi[j], 0.f));
            }
        }

        for (int i = t; i < 16 * EH2_; i += 256) {
            int col = i >> 7, k = i & 127;
            float v = (col < EO_) ? Ew3[(size_t)e * EH2_ * EO_ + k * EO_ + col] : 0.f;
            E3t[col * H2P + k] = f2bf(v);
        }
        __syncthreads();

        {
            const int g = wave;
            f32x4 acc3 = {};
            #pragma unroll
            for (int kc = 0; kc < 4; ++kc) {
                s16x8 a = *(const s16x8*)&h2L[(g * 16 + l16) * H2P + kc * 32 + quad * 8];
                s16x8 b = *(const s16x8*)&E3t[l16 * H2P + kc * 32 + quad * 8];
                acc3 = __builtin_amdgcn_mfma_f32_16x16x32_bf16(a, b, acc3, 0, 0, 0);
            }
            if (l16 < EO_) {
                float b3 = Eb3[e * EO_ + l16];
                #pragma unroll
                for (int r = 0; r < 4; ++r) {
                    int row = m0 + g * 16 + quad * 4 + r;
                    eo[(size_t)row * (E_ * EO_) + e * EO_ + l16] = acc3[r] + b3;
                }
            }
        }
        return;
    }

    // ===================== GATE branch (dense tile table) =================
    {
        const int gidx = (blockIdx.y - E_) * gridDim.x + blockIdx.x;
        if (gidx >= ngt[0]) return;
        const int entry = gtab[gidx];
        const int d     = entry >> 16;
        const int start = (entry & 0xffff) * 64;
        const int base  = gbase[d];
        const int cnt   = hist[d];

        // carve gate LDS out of smem (byte offsets; all within 53248)
        ushort* gAs  = smem;                                   // 4096 B
        ushort* gBs  = smem + 2048;                            // 4096 B
        int*    ridx = (int*)(smem + 4096);                    // 256 B @8192
        float (*gh)[GH_ + 1] = (float(*)[GH_ + 1])(smem + 4224);   // 16640 B @8448
        float*  w2s  = (float*)(smem + 12544);                 // 1536 B @25088
        float*  b2s  = (float*)(smem + 13312);                 // 24 B @26624
        float (*lg)[E_] = (float(*)[E_])(smem + 13324);        // 1536 B @26648

        const int qsw = (quad ^ ((l16 >> 1) & 3)) * 8;

        if (t < 64) {
            int p = start + t;
            ridx[t] = (p < cnt) ? perm[base + p] : perm[base];  // clamp OOB
        }
        for (int i = t; i < GH_ * E_; i += 256) w2s[i] = Gw2[(size_t)d * GH_ * E_ + i];
        if (t < E_) b2s[t] = Gb2[d * E_ + t];
        __syncthreads();

        const int srow = t >> 2;
        const int sw   = ((t & 3) ^ ((srow >> 1) & 3)) * 8;
        const int myRow = ridx[srow];
        const ushort* aRow = xb + (size_t)myRow * IN_ + sw;
        const ushort* bRow = Gw1t + (size_t)d * GH_ * IN_ + (size_t)srow * IN_ + sw;

        f32x4 acc[4] = {};
        for (int k0 = 0; k0 < IN_; k0 += 32) {
            GLOBAL_LDS16(aRow + k0, gAs + wave * 512);
            GLOBAL_LDS16(bRow + k0, gBs + wave * 512);
            __syncthreads();

            s16x8 bf = *(const s16x8*)&gBs[(wave * 16 + l16) * 32 + qsw];
            #pragma unroll
            for (int i = 0; i < 4; ++i) {
                s16x8 af = *(const s16x8*)&gAs[(16 * i + l16) * 32 + qsw];
                acc[i] = __builtin_amdgcn_mfma_f32_16x16x32_bf16(af, bf, acc[i], 0, 0, 0);
            }
            __syncthreads();
        }

        const int hcol = wave * 16 + l16;
        float hb = Gb1[d * GH_ + hcol];
        #pragma unroll
        for (int i = 0; i < 4; ++i)
            #pragma unroll
            for (int r = 0; r < 4; ++r)
                gh[16 * i + quad * 4 + r][hcol] = fmaxf(acc[i][r] + hb, 0.f);
        __syncthreads();

        for (int p = t; p < 64 * E_; p += 256) {
            int row = p / E_, e = p - row * E_;
            float s = b2s[e];
            #pragma unroll 8
            for (int h = 0; h < GH_; ++h) s += gh[row][h] * w2s[h * E_ + e];
            lg[row][e] = s;
        }
        __syncthreads();

        if (t < 64 && start + t < cnt) {
            int b = ridx[t];
            float mx = lg[t][0];
            #pragma unroll
            for (int e = 1; e < E_; ++e) mx = fmaxf(mx, lg[t][e]);
            float ex[E_], sum = 0.f;
            #pragma unroll
            for (int e = 0; e < E_; ++e) { ex[e] = expf(lg[t][e] - mx); sum += ex[e]; }
            float inv = 1.f / sum;
            #pragma unroll
            for (int e = 0; e < E_; ++e) gate[(size_t)b * E_ + e] = ex[e] * inv;
        }
    }
}

// ---------------------------------------------------------------------------
// Final: MMoE combine + avg + tower, one wave per sample
// ---------------------------------------------------------------------------
__global__ __launch_bounds__(256) void k_final(
        const float* __restrict__ eo, const float* __restrict__ gate,
        const int* __restrict__ dom,
        const float* __restrict__ Tw1, const float* __restrict__ Tb1,
        const float* __restrict__ Tw2, const float* __restrict__ Tb2,
        float* __restrict__ out) {
    const int wave = threadIdx.x >> 6;
    const int lane = threadIdx.x & 63;
    const int b = blockIdx.x * 4 + wave;
    const int d = dom[b];

    const float* eob = eo + (size_t)b * (E_ * EO_);
    float g[E_];
    #pragma unroll
    for (int e = 0; e < E_; ++e) g[e] = gate[(size_t)b * E_ + e];

    float mmoe[EO_], avg[EO_];
    #pragma unroll
    for (int o = 0; o < EO_; ++o) {
        float m = 0.f, a = 0.f;
        #pragma unroll
        for (int e = 0; e < E_; ++e) {
            float v = eob[e * EO_ + o];
            m += g[e] * v;
            a += v;
        }
        mmoe[o] = m;
        avg[o] = a * (1.0f / E_);
    }

    float acc = Tb1[d * TH_ + lane];
    #pragma unroll
    for (int o = 0; o < EO_; ++o)
        acc += mmoe[o] * Tw1[(size_t)d * EO_ * TH_ + o * TH_ + lane];
    acc = fmaxf(acc, 0.f);

    float s = acc * Tw2[d * TH_ + lane];
    #pragma unroll
    for (int off = 32; off >= 1; off >>= 1) s += __shfl_xor(s, off, 64);

    if (lane == 0)
        out[b] = 1.f / (1.f + expf(-(s + Tb2[d])));
    if (lane < EO_) {
        out[B_ + (size_t)b * EO_ + lane] = avg[lane];
        out[B_ + (size_t)B_ * EO_ + (size_t)b * EO_ + lane] = mmoe[lane];
    }
}

// ---------------------------------------------------------------------------
extern "C" void kernel_launch(void* const* d_in, const int* in_sizes, int n_in,
                              void* d_out, int out_size, void* d_ws, size_t ws_size,
                              hipStream_t stream) {
    const float* x   = (const float*)d_in[0];
    const int*   dom = (const int*)d_in[1];
    const float* Ew1 = (const float*)d_in[2];
    const float* Eb1 = (const float*)d_in[3];
    const float* Ew2 = (const float*)d_in[4];
    const float* Eb2 = (const float*)d_in[5];
    const float* Ew3 = (const float*)d_in[6];
    const float* Eb3 = (const float*)d_in[7];
    const float* Gw1 = (const float*)d_in[8];
    const float* Gb1 = (const float*)d_in[9];
    const float* Gw2 = (const float*)d_in[10];
    const float* Gb2 = (const float*)d_in[11];
    const float* Tw1 = (const float*)d_in[12];
    const float* Tb1 = (const float*)d_in[13];
    const float* Tw2 = (const float*)d_in[14];
    const float* Tb2 = (const float*)d_in[15];
    float* out = (float*)d_out;

    char* ws = (char*)d_ws;
    size_t off = 0;
    auto take = [&](size_t bytes) -> char* {
        char* p = ws + off;
        off = (off + bytes + 255) & ~(size_t)255;
        return p;
    };
    int*    hist    = (int*)take(D_ * 4);
    int*    cursor0 = (int*)take(D_ * 4);
    int*    gbase   = (int*)take(D_ * 4);
    int*    gtab    = (int*)take(512 * 4);
    int*    ngt     = (int*)take(4);
    int*    perm    = (int*)take(B_ * 4);
    float*  gateBuf = (float*)take((size_t)B_ * E_ * 4);
    float*  eoBuf   = (float*)take((size_t)B_ * E_ * EO_ * 4);
    ushort* xb      = (ushort*)take((size_t)B_ * IN_ * 2);
    ushort* W1t     = (ushort*)take((size_t)E_ * IN_ * EH1_ * 2);
    ushort* W2t     = (ushort*)take((size_t)E_ * EH1_ * EH2_ * 2);
    ushort* G1t     = (ushort*)take((size_t)D_ * IN_ * GH_ * 2);

    // zero hist + cursor0 (adjacent 256B-aligned takes)
    hipMemsetAsync(hist, 0, (size_t)((char*)gbase - (char*)hist), stream);

    // fused conversions (cvt + weight transposes + histogram)
    k_prep<<<dim3(PREP_BLKS), dim3(256), 0, stream>>>(
        x, xb, Ew1, W1t, Ew2, W2t, Gw1, G1t, dom, hist);

    // chunked scatter + gate-tile table build
    k_scatter2<<<dim3(B_ / 256), dim3(256), 0, stream>>>(
        dom, hist, cursor0, perm, gbase, gtab, ngt);

    // merged: experts (y<6, fused L1+L2+L3) + gates (y>=6, dense table)
    k_eg<<<dim3(B_ / 64, GY_), dim3(256), 0, stream>>>(
        xb, W1t, Eb1, W2t, Eb2, Ew3, Eb3, eoBuf,
        G1t, Gb1, Gw2, Gb2, perm, hist, gbase, gtab, ngt, gateBuf);

    // combine + towers + outputs
    k_final<<<dim3(B_ / 4), dim3(256), 0, stream>>>(
        eoBuf, gateBuf, dom, Tw1, Tb1, Tw2, Tb2, out);
}

// Round 5
// 241.346 us; speedup vs baseline: 1.3568x; 1.0613x over previous
//
#include <hip/hip_runtime.h>
#include <hip/hip_bf16.h>
#include <math.h>

// Problem constants (HC2MMoE)
#define B_    16384
#define IN_   1024
#define E_    6
#define D_    20
#define EH1_  256
#define EH2_  128
#define EO_   10
#define GH_   64
#define TH_   64

typedef short  s16x8  __attribute__((ext_vector_type(8)));   // 8 bf16 = 4 VGPRs
typedef float  f32x4  __attribute__((ext_vector_type(4)));
typedef float  f32x16 __attribute__((ext_vector_type(16)));

__device__ inline ushort f2bf(float f) {   // RNE fp32 -> bf16 bits
    union { float f; uint32_t u; } v; v.f = f;
    return (ushort)((v.u + 0x7fffu + ((v.u >> 16) & 1u)) >> 16);
}

#define GLOBAL_LDS16(g, l)                                                     \
    __builtin_amdgcn_global_load_lds(                                          \
        (const __attribute__((address_space(1))) void*)(g),                    \
        (__attribute__((address_space(3))) void*)(l), 16, 0, 0)

#define NCHUNK (B_ / 256)   // 64

// ---------------------------------------------------------------------------
// Prep: fused x-convert (grid-strided) + 3 weight transposes + per-chunk
// domain counts (no atomics, no zero-init needed: each block owns its row).
// ---------------------------------------------------------------------------
#define CVT_BLKS  2048
#define CVT_ITERS (B_ * IN_ / 4 / 256 / CVT_BLKS)            // 8
#define WT1_TILES ((EH1_ / 32) * (IN_ / 32) * E_)            // 1536
#define WT2_TILES ((EH2_ / 32) * (EH1_ / 32) * E_)           // 192
#define WTG_TILES ((GH_ / 32) * (IN_ / 32) * D_)             // 1280
#define PREP_BLKS (CVT_BLKS + WT1_TILES + WT2_TILES + WTG_TILES + NCHUNK)

__global__ __launch_bounds__(256) void k_prep(
        const float* __restrict__ x, ushort* __restrict__ xb,
        const float* __restrict__ Ew1, ushort* __restrict__ W1t,
        const float* __restrict__ Ew2, ushort* __restrict__ W2t,
        const float* __restrict__ Gw1, ushort* __restrict__ G1t,
        const int* __restrict__ dom, int* __restrict__ cnts) {
    __shared__ float tile[32][33];
    __shared__ int hcnt[D_];
    int bid = blockIdx.x;
    const int t = threadIdx.x;

    if (bid < CVT_BLKS) {
        int i = bid * 256 + t;
        #pragma unroll
        for (int it = 0; it < CVT_ITERS; ++it, i += CVT_BLKS * 256) {
            float4 v = ((const float4*)x)[i];
            ushort4 o;
            o.x = f2bf(v.x); o.y = f2bf(v.y); o.z = f2bf(v.z); o.w = f2bf(v.w);
            ((ushort4*)xb)[i] = o;
        }
        return;
    }
    bid -= CVT_BLKS;

    const float* W; ushort* Wt; int K, N, z, ky, nx;
    if (bid < WT1_TILES) {
        W = Ew1; Wt = W1t; K = IN_; N = EH1_;
        z = bid / (8 * 32); int r = bid % (8 * 32); ky = r / 8; nx = r % 8;
    } else if (bid < WT1_TILES + WT2_TILES) {
        bid -= WT1_TILES;
        W = Ew2; Wt = W2t; K = EH1_; N = EH2_;
        z = bid / (4 * 8); int r = bid % (4 * 8); ky = r / 4; nx = r % 4;
    } else if (bid < WT1_TILES + WT2_TILES + WTG_TILES) {
        bid -= WT1_TILES + WT2_TILES;
        W = Gw1; Wt = G1t; K = IN_; N = GH_;
        z = bid / (2 * 32); int r = bid % (2 * 32); ky = r / 2; nx = r % 2;
    } else {
        // per-chunk count blocks: 256 samples each, LDS counts -> direct write
        int c = bid - (WT1_TILES + WT2_TILES + WTG_TILES);
        if (t < D_) hcnt[t] = 0;
        __syncthreads();
        atomicAdd(&hcnt[dom[c * 256 + t]], 1);
        __syncthreads();
        if (t < D_) cnts[c * D_ + t] = hcnt[t];
        return;
    }
    const int n0 = nx * 32, k0 = ky * 32;
    const float* We = W + (size_t)z * K * N;
    ushort* Wte = Wt + (size_t)z * K * N;
    const int lx = t & 31, ly = t >> 5;
    #pragma unroll
    for (int r = 0; r < 4; ++r)
        tile[ly + r * 8][lx] = We[(size_t)(k0 + ly + r * 8) * N + n0 + lx];
    __syncthreads();
    #pragma unroll
    for (int r = 0; r < 4; ++r)
        Wte[(size_t)(n0 + ly + r * 8) * K + k0 + lx] = f2bf(tile[lx][ly + r * 8]);
}

#define GBK 32
#define H2P 136

// ---------------------------------------------------------------------------
// L1 GEMM (R8-verified 128x128/BK=32 structure, 76us measured) for all 6
// experts, PLUS a z==E_ slice doing the deterministic scatter (chunk bases
// from the counts table, zero global atomics) and gate-table build.
// ---------------------------------------------------------------------------
__global__ __launch_bounds__(256) void k_gemm(
        const ushort* __restrict__ A, const ushort* __restrict__ Wt,
        const float* __restrict__ Bias, ushort* __restrict__ C,
        const int* __restrict__ dom, const int* __restrict__ cnts,
        int* __restrict__ perm, int* __restrict__ gbaseG,
        int* __restrict__ histG, int* __restrict__ gtab,
        int* __restrict__ ngt) {
    if (blockIdx.z == E_) {
        // ---------------- scatter slice ----------------
        if (blockIdx.x != 0 || blockIdx.y >= NCHUNK) return;
        __shared__ int tot[D_], lbase[D_], lcnt[D_];
        const int c = blockIdx.y;
        const int t = threadIdx.x;
        if (t < D_) {
            int before = 0, total = 0;
            for (int cc = 0; cc < NCHUNK; ++cc) {
                int v = cnts[cc * D_ + t];
                if (cc < c) before += v;
                total += v;
            }
            tot[t] = total; lbase[t] = before; lcnt[t] = 0;
        }
        __syncthreads();
        if (t < D_) {
            int gb = 0;
            #pragma unroll
            for (int d2 = 0; d2 < D_; ++d2) if (d2 < t) gb += tot[d2];
            lbase[t] += gb;
            if (c == 0) { gbaseG[t] = gb; histG[t] = tot[t]; }
        }
        __syncthreads();
        if (c == 0 && t == 0) {
            int n = 0;
            for (int d2 = 0; d2 < D_; ++d2) {
                int nt = (tot[d2] + 63) >> 6;
                for (int tt = 0; tt < nt; ++tt) gtab[n++] = (d2 << 16) | tt;
            }
            ngt[0] = n;
        }
        const int g = c * 256 + t;
        const int d = dom[g];
        int r = atomicAdd(&lcnt[d], 1);          // LDS-only, rank within chunk
        perm[lbase[d] + r] = g;
        return;
    }

    // ---------------- expert L1 GEMM (byte-identical to verified R8) ------
    __shared__ __attribute__((aligned(16))) ushort As[128 * GBK];
    __shared__ __attribute__((aligned(16))) ushort Bs[128 * GBK];

    const int e = blockIdx.z;
    const ushort* Ae = A;
    const ushort* We = Wt + (size_t)e * (size_t)EH1_ * IN_;
    const float* BiasE = Bias + (size_t)e * EH1_;
    ushort* Ce = C + (size_t)e * (size_t)B_ * EH1_;

    const int m0 = blockIdx.y * 128;
    const int n0 = blockIdx.x * 128;
    const int t = threadIdx.x;
    const int wave = t >> 6;
    const int lane = t & 63;

    const int q0 = wave * 2, q1 = q0 + 1;
    const int sr0 = q0 * 16 + (lane >> 2);
    const int sr1 = sr0 + 16;
    const int sw  = ((lane & 3) ^ ((sr0 >> 1) & 3)) * 8;

    const int l32  = lane & 31;
    const int ksel = lane >> 5;
    const int rw = (wave & 1) * 64;
    const int cw = (wave >> 1) * 64;

    int rowA[2], rowB[2], swzA[2], swzB[2];
    #pragma unroll
    for (int i = 0; i < 2; ++i) {
        rowA[i] = rw + 32 * i + l32;  swzA[i] = (rowA[i] >> 1) & 3;
        rowB[i] = cw + 32 * i + l32;  swzB[i] = (rowB[i] >> 1) & 3;
    }

    f32x16 acc[2][2] = {};

    for (int k0 = 0; k0 < IN_; k0 += GBK) {
        GLOBAL_LDS16(Ae + (size_t)(m0 + sr0) * IN_ + k0 + sw, As + q0 * 512);
        GLOBAL_LDS16(Ae + (size_t)(m0 + sr1) * IN_ + k0 + sw, As + q1 * 512);
        GLOBAL_LDS16(We + (size_t)(n0 + sr0) * IN_ + k0 + sw, Bs + q0 * 512);
        GLOBAL_LDS16(We + (size_t)(n0 + sr1) * IN_ + k0 + sw, Bs + q1 * 512);
        __syncthreads();

        #pragma unroll
        for (int h = 0; h < 2; ++h) {
            const int cb = h * 2 + ksel;
            s16x8 af[2], bf[2];
            #pragma unroll
            for (int i = 0; i < 2; ++i)
                af[i] = *(const s16x8*)&As[rowA[i] * GBK + ((cb ^ swzA[i]) * 8)];
            #pragma unroll
            for (int j = 0; j < 2; ++j)
                bf[j] = *(const s16x8*)&Bs[rowB[j] * GBK + ((cb ^ swzB[j]) * 8)];
            #pragma unroll
            for (int i = 0; i < 2; ++i)
                #pragma unroll
                for (int j = 0; j < 2; ++j)
                    acc[i][j] = __builtin_amdgcn_mfma_f32_32x32x16_bf16(
                        af[i], bf[j], acc[i][j], 0, 0, 0);
        }
        __syncthreads();
    }

    float bi[2];
    #pragma unroll
    for (int j = 0; j < 2; ++j) bi[j] = BiasE[n0 + cw + 32 * j + l32];

    #pragma unroll
    for (int i = 0; i < 2; ++i) {
        #pragma unroll
        for (int reg = 0; reg < 16; ++reg) {
            int rowin = (reg & 3) + 8 * (reg >> 2) + 4 * ksel;
            ushort* crow = Ce + (size_t)(m0 + rw + 32 * i + rowin) * EH1_;
            #pragma unroll
            for (int j = 0; j < 2; ++j) {
                float v = fmaxf(acc[i][j][reg] + bi[j], 0.f);
                crow[n0 + cw + 32 * j + l32] = f2bf(v);
            }
        }
    }
}

#define GYL (E_ + 3)   // 6 l2eo expert slices + 3 gate-table slices

// ---------------------------------------------------------------------------
// Fused expert L2+L3 (verified R8 path) for y<6; gate tiles (dense table)
// for y>=6. Gate overlaps l2eo's 768 blocks instead of tailing the big GEMM.
// ---------------------------------------------------------------------------
__global__ __launch_bounds__(256) void k_l2eog(
        const ushort* __restrict__ h1, const ushort* __restrict__ W2t,
        const float* __restrict__ Eb2, const float* __restrict__ Ew3,
        const float* __restrict__ Eb3, float* __restrict__ eo,
        const ushort* __restrict__ xb, const ushort* __restrict__ Gw1t,
        const float* __restrict__ Gb1, const float* __restrict__ Gw2,
        const float* __restrict__ Gb2, const int* __restrict__ perm,
        const int* __restrict__ histG, const int* __restrict__ gbaseG,
        const int* __restrict__ gtab, const int* __restrict__ ngt,
        float* __restrict__ gate) {
    __shared__ __attribute__((aligned(16))) ushort smem[17408 + 16 * H2P];

    const int t = threadIdx.x;
    const int wave = t >> 6;
    const int lane = t & 63;
    const int quad = lane >> 4;
    const int l16  = lane & 15;
    const int l32  = lane & 31;
    const int ksel = lane >> 5;

    if (blockIdx.y < E_) {
        // ================= L2+L3 branch (verified R8 path) ================
        ushort* As = smem;            // 128*32 elems
        ushort* Bs = smem + 4096;     // 128*32 elems

        const int e = blockIdx.y;
        const ushort* Ae = h1 + (size_t)e * B_ * EH1_;
        const ushort* We = W2t + (size_t)e * EH2_ * EH1_;

        const int m0 = blockIdx.x * 128;

        const int q0 = wave * 2, q1 = q0 + 1;
        const int sr0 = q0 * 16 + (lane >> 2);
        const int sr1 = sr0 + 16;
        const int sw  = ((lane & 3) ^ ((sr0 >> 1) & 3)) * 8;

        const int rw = (wave & 1) * 64;
        const int cw = (wave >> 1) * 64;

        int rowA[2], rowB[2], swzA[2], swzB[2];
        #pragma unroll
        for (int i = 0; i < 2; ++i) {
            rowA[i] = rw + 32 * i + l32;  swzA[i] = (rowA[i] >> 1) & 3;
            rowB[i] = cw + 32 * i + l32;  swzB[i] = (rowB[i] >> 1) & 3;
        }

        f32x16 acc[2][2] = {};

        for (int k0 = 0; k0 < EH1_; k0 += GBK) {
            GLOBAL_LDS16(Ae + (size_t)(m0 + sr0) * EH1_ + k0 + sw, As + q0 * 512);
            GLOBAL_LDS16(Ae + (size_t)(m0 + sr1) * EH1_ + k0 + sw, As + q1 * 512);
            GLOBAL_LDS16(We + (size_t)sr0 * EH1_ + k0 + sw, Bs + q0 * 512);
            GLOBAL_LDS16(We + (size_t)sr1 * EH1_ + k0 + sw, Bs + q1 * 512);
            __syncthreads();

            #pragma unroll
            for (int h = 0; h < 2; ++h) {
                const int cb = h * 2 + ksel;
                s16x8 af[2], bf[2];
                #pragma unroll
                for (int i = 0; i < 2; ++i)
                    af[i] = *(const s16x8*)&As[rowA[i] * GBK + ((cb ^ swzA[i]) * 8)];
                #pragma unroll
                for (int j = 0; j < 2; ++j)
                    bf[j] = *(const s16x8*)&Bs[rowB[j] * GBK + ((cb ^ swzB[j]) * 8)];
                #pragma unroll
                for (int i = 0; i < 2; ++i)
                    #pragma unroll
                    for (int j = 0; j < 2; ++j)
                        acc[i][j] = __builtin_amdgcn_mfma_f32_32x32x16_bf16(
                            af[i], bf[j], acc[i][j], 0, 0, 0);
            }
            __syncthreads();
        }

        // epilogue: h2 tile (bias+relu, bf16) -> LDS, 32x32 C/D scatter
        ushort* h2L = smem;             // [128][H2P]
        ushort* E3t = smem + 128 * H2P; // [16][H2P]

        float bi[2];
        #pragma unroll
        for (int j = 0; j < 2; ++j) bi[j] = Eb2[e * EH2_ + cw + 32 * j + l32];

        #pragma unroll
        for (int i = 0; i < 2; ++i)
            #pragma unroll
            for (int reg = 0; reg < 16; ++reg) {
                int rowin = (reg & 3) + 8 * (reg >> 2) + 4 * ksel;
                int row = rw + 32 * i + rowin;
                #pragma unroll
                for (int j = 0; j < 2; ++j)
                    h2L[row * H2P + cw + 32 * j + l32] =
                        f2bf(fmaxf(acc[i][j][reg] + bi[j], 0.f));
            }

        for (int i = t; i < 16 * 128; i += 256) {
            int col = i >> 7, k = i & 127;
            float v = (col < EO_) ? Ew3[(size_t)e * EH2_ * EO_ + k * EO_ + col] : 0.f;
            E3t[col * H2P + k] = f2bf(v);
        }
        __syncthreads();

        #pragma unroll
        for (int gi = 0; gi < 2; ++gi) {
            int g = wave * 2 + gi;
            f32x4 acc2 = {};
            #pragma unroll
            for (int kc = 0; kc < 4; ++kc) {
                s16x8 a = *(const s16x8*)&h2L[(g * 16 + l16) * H2P + kc * 32 + quad * 8];
                s16x8 b = *(const s16x8*)&E3t[l16 * H2P + kc * 32 + quad * 8];
                acc2 = __builtin_amdgcn_mfma_f32_16x16x32_bf16(a, b, acc2, 0, 0, 0);
            }
            if (l16 < EO_) {
                float b3 = Eb3[e * EO_ + l16];
                #pragma unroll
                for (int r = 0; r < 4; ++r) {
                    int row = m0 + g * 16 + quad * 4 + r;
                    eo[(size_t)row * (E_ * EO_) + e * EO_ + l16] = acc2[r] + b3;
                }
            }
        }
        return;
    }

    // ===================== GATE branch (dense tile table) =================
    {
        const int gidx = (blockIdx.y - E_) * gridDim.x + blockIdx.x;
        if (gidx >= ngt[0]) return;
        const int entry = gtab[gidx];
        const int d     = entry >> 16;
        const int start = (entry & 0xffff) * 64;
        const int base  = gbaseG[d];
        const int cnt   = histG[d];

        // carve gate LDS out of smem (byte offsets; total smem = 39168 B)
        ushort* gAs  = smem;                                   // 4096 B @0
        ushort* gBs  = smem + 2048;                            // 4096 B @4096
        int*    ridx = (int*)(smem + 4096);                    // 256 B  @8192
        float (*gh)[GH_ + 1] = (float(*)[GH_ + 1])(smem + 4224);  // 16640 B @8448
        float*  w2s  = (float*)(smem + 12544);                 // 1536 B @25088
        float*  b2s  = (float*)(smem + 13312);                 // 24 B   @26624
        float (*lg)[E_] = (float(*)[E_])(smem + 13324);        // 1536 B @26648

        const int qsw = (quad ^ ((l16 >> 1) & 3)) * 8;

        if (t < 64) {
            int p = start + t;
            ridx[t] = (p < cnt) ? perm[base + p] : perm[base];  // clamp OOB
        }
        for (int i = t; i < GH_ * E_; i += 256) w2s[i] = Gw2[(size_t)d * GH_ * E_ + i];
        if (t < E_) b2s[t] = Gb2[d * E_ + t];
        __syncthreads();

        const int srow = t >> 2;
        const int sw   = ((t & 3) ^ ((srow >> 1) & 3)) * 8;
        const int myRow = ridx[srow];
        const ushort* aRow = xb + (size_t)myRow * IN_ + sw;
        const ushort* bRow = Gw1t + (size_t)d * GH_ * IN_ + (size_t)srow * IN_ + sw;

        f32x4 acc[4] = {};
        for (int k0 = 0; k0 < IN_; k0 += 32) {
            GLOBAL_LDS16(aRow + k0, gAs + wave * 512);
            GLOBAL_LDS16(bRow + k0, gBs + wave * 512);
            __syncthreads();

            s16x8 bf = *(const s16x8*)&gBs[(wave * 16 + l16) * 32 + qsw];
            #pragma unroll
            for (int i = 0; i < 4; ++i) {
                s16x8 af = *(const s16x8*)&gAs[(16 * i + l16) * 32 + qsw];
                acc[i] = __builtin_amdgcn_mfma_f32_16x16x32_bf16(af, bf, acc[i], 0, 0, 0);
            }
            __syncthreads();
        }

        const int hcol = wave * 16 + l16;
        float hb = Gb1[d * GH_ + hcol];
        #pragma unroll
        for (int i = 0; i < 4; ++i)
            #pragma unroll
            for (int r = 0; r < 4; ++r)
                gh[16 * i + quad * 4 + r][hcol] = fmaxf(acc[i][r] + hb, 0.f);
        __syncthreads();

        for (int p = t; p < 64 * E_; p += 256) {
            int row = p / E_, e = p - row * E_;
            float s = b2s[e];
            #pragma unroll 8
            for (int h = 0; h < GH_; ++h) s += gh[row][h] * w2s[h * E_ + e];
            lg[row][e] = s;
        }
        __syncthreads();

        if (t < 64 && start + t < cnt) {
            int b = ridx[t];
            float mx = lg[t][0];
            #pragma unroll
            for (int e = 1; e < E_; ++e) mx = fmaxf(mx, lg[t][e]);
            float ex[E_], sum = 0.f;
            #pragma unroll
            for (int e = 0; e < E_; ++e) { ex[e] = expf(lg[t][e] - mx); sum += ex[e]; }
            float inv = 1.f / sum;
            #pragma unroll
            for (int e = 0; e < E_; ++e) gate[(size_t)b * E_ + e] = ex[e] * inv;
        }
    }
}

// ---------------------------------------------------------------------------
// Final: MMoE combine + avg + tower, one wave per sample
// ---------------------------------------------------------------------------
__global__ __launch_bounds__(256) void k_final(
        const float* __restrict__ eo, const float* __restrict__ gate,
        const int* __restrict__ dom,
        const float* __restrict__ Tw1, const float* __restrict__ Tb1,
        const float* __restrict__ Tw2, const float* __restrict__ Tb2,
        float* __restrict__ out) {
    const int wave = threadIdx.x >> 6;
    const int lane = threadIdx.x & 63;
    const int b = blockIdx.x * 4 + wave;
    const int d = dom[b];

    const float* eob = eo + (size_t)b * (E_ * EO_);
    float g[E_];
    #pragma unroll
    for (int e = 0; e < E_; ++e) g[e] = gate[(size_t)b * E_ + e];

    float mmoe[EO_], avg[EO_];
    #pragma unroll
    for (int o = 0; o < EO_; ++o) {
        float m = 0.f, a = 0.f;
        #pragma unroll
        for (int e = 0; e < E_; ++e) {
            float v = eob[e * EO_ + o];
            m += g[e] * v;
            a += v;
        }
        mmoe[o] = m;
        avg[o] = a * (1.0f / E_);
    }

    float acc = Tb1[d * TH_ + lane];
    #pragma unroll
    for (int o = 0; o < EO_; ++o)
        acc += mmoe[o] * Tw1[(size_t)d * EO_ * TH_ + o * TH_ + lane];
    acc = fmaxf(acc, 0.f);

    float s = acc * Tw2[d * TH_ + lane];
    #pragma unroll
    for (int off = 32; off >= 1; off >>= 1) s += __shfl_xor(s, off, 64);

    if (lane == 0)
        out[b] = 1.f / (1.f + expf(-(s + Tb2[d])));
    if (lane < EO_) {
        out[B_ + (size_t)b * EO_ + lane] = avg[lane];
        out[B_ + (size_t)B_ * EO_ + (size_t)b * EO_ + lane] = mmoe[lane];
    }
}

// ---------------------------------------------------------------------------
extern "C" void kernel_launch(void* const* d_in, const int* in_sizes, int n_in,
                              void* d_out, int out_size, void* d_ws, size_t ws_size,
                              hipStream_t stream) {
    const float* x   = (const float*)d_in[0];
    const int*   dom = (const int*)d_in[1];
    const float* Ew1 = (const float*)d_in[2];
    const float* Eb1 = (const float*)d_in[3];
    const float* Ew2 = (const float*)d_in[4];
    const float* Eb2 = (const float*)d_in[5];
    const float* Ew3 = (const float*)d_in[6];
    const float* Eb3 = (const float*)d_in[7];
    const float* Gw1 = (const float*)d_in[8];
    const float* Gb1 = (const float*)d_in[9];
    const float* Gw2 = (const float*)d_in[10];
    const float* Gb2 = (const float*)d_in[11];
    const float* Tw1 = (const float*)d_in[12];
    const float* Tb1 = (const float*)d_in[13];
    const float* Tw2 = (const float*)d_in[14];
    const float* Tb2 = (const float*)d_in[15];
    float* out = (float*)d_out;

    char* ws = (char*)d_ws;
    size_t off = 0;
    auto take = [&](size_t bytes) -> char* {
        char* p = ws + off;
        off = (off + bytes + 255) & ~(size_t)255;
        return p;
    };
    int*    cnts    = (int*)take((size_t)NCHUNK * D_ * 4);
    int*    histG   = (int*)take(D_ * 4);
    int*    gbaseG  = (int*)take(D_ * 4);
    int*    gtab    = (int*)take(512 * 4);
    int*    ngt     = (int*)take(4);
    int*    perm    = (int*)take(B_ * 4);
    float*  gateBuf = (float*)take((size_t)B_ * E_ * 4);
    float*  eoBuf   = (float*)take((size_t)B_ * E_ * EO_ * 4);
    ushort* xb      = (ushort*)take((size_t)B_ * IN_ * 2);
    ushort* W1t     = (ushort*)take((size_t)E_ * IN_ * EH1_ * 2);
    ushort* W2t     = (ushort*)take((size_t)E_ * EH1_ * EH2_ * 2);
    ushort* G1t     = (ushort*)take((size_t)D_ * IN_ * GH_ * 2);
    ushort* h1      = (ushort*)take((size_t)E_ * B_ * EH1_ * 2);

    // 1) conversions + transposes + per-chunk counts (no memset needed)
    k_prep<<<dim3(PREP_BLKS), dim3(256), 0, stream>>>(
        x, xb, Ew1, W1t, Ew2, W2t, Gw1, G1t, dom, cnts);

    // 2) L1 GEMM (all experts) + deterministic scatter slice (z==6)
    k_gemm<<<dim3(EH1_ / 128, B_ / 128, E_ + 1), dim3(256), 0, stream>>>(
        xb, W1t, Eb1, h1, dom, cnts, perm, gbaseG, histG, gtab, ngt);

    // 3) fused L2+L3 (y<6) + gates (y>=6, dense table)
    k_l2eog<<<dim3(B_ / 128, GYL), dim3(256), 0, stream>>>(
        h1, W2t, Eb2, Ew3, Eb3, eoBuf,
        xb, G1t, Gb1, Gw2, Gb2, perm, histG, gbaseG, gtab, ngt, gateBuf);

    // 4) combine + towers + outputs
    k_final<<<dim3(B_ / 4), dim3(256), 0, stream>>>(
        eoBuf, gateBuf, dom, Tw1, Tb1, Tw2, Tb2, out);
}

// Round 6
// 241.073 us; speedup vs baseline: 1.3583x; 1.0011x over previous
//
#include <hip/hip_runtime.h>
#include <hip/hip_bf16.h>
#include <math.h>

// Problem constants (HC2MMoE)
#define B_    16384
#define IN_   1024
#define E_    6
#define D_    20
#define EH1_  256
#define EH2_  128
#define EO_   10
#define GH_   64
#define TH_   64

typedef short  s16x8  __attribute__((ext_vector_type(8)));   // 8 bf16 = 4 VGPRs
typedef float  f32x4  __attribute__((ext_vector_type(4)));
typedef float  f32x16 __attribute__((ext_vector_type(16)));

__device__ inline ushort f2bf(float f) {   // RNE fp32 -> bf16 bits
    union { float f; uint32_t u; } v; v.f = f;
    return (ushort)((v.u + 0x7fffu + ((v.u >> 16) & 1u)) >> 16);
}

#define GLOBAL_LDS16(g, l)                                                     \
    __builtin_amdgcn_global_load_lds(                                          \
        (const __attribute__((address_space(1))) void*)(g),                    \
        (__attribute__((address_space(3))) void*)(l), 16, 0, 0)

#define NCHUNK (B_ / 256)   // 64

// ---------------------------------------------------------------------------
// Prep: fused x-convert (grid-strided) + 3 weight transposes + per-chunk
// domain counts (no atomics, no zero-init needed: each block owns its row).
// ---------------------------------------------------------------------------
#define CVT_BLKS  2048
#define CVT_ITERS (B_ * IN_ / 4 / 256 / CVT_BLKS)            // 8
#define WT1_TILES ((EH1_ / 32) * (IN_ / 32) * E_)            // 1536
#define WT2_TILES ((EH2_ / 32) * (EH1_ / 32) * E_)           // 192
#define WTG_TILES ((GH_ / 32) * (IN_ / 32) * D_)             // 1280
#define PREP_BLKS (CVT_BLKS + WT1_TILES + WT2_TILES + WTG_TILES + NCHUNK)

__global__ __launch_bounds__(256) void k_prep(
        const float* __restrict__ x, ushort* __restrict__ xb,
        const float* __restrict__ Ew1, ushort* __restrict__ W1t,
        const float* __restrict__ Ew2, ushort* __restrict__ W2t,
        const float* __restrict__ Gw1, ushort* __restrict__ G1t,
        const int* __restrict__ dom, int* __restrict__ cnts) {
    __shared__ float tile[32][33];
    __shared__ int hcnt[D_];
    int bid = blockIdx.x;
    const int t = threadIdx.x;

    if (bid < CVT_BLKS) {
        int i = bid * 256 + t;
        #pragma unroll
        for (int it = 0; it < CVT_ITERS; ++it, i += CVT_BLKS * 256) {
            float4 v = ((const float4*)x)[i];
            ushort4 o;
            o.x = f2bf(v.x); o.y = f2bf(v.y); o.z = f2bf(v.z); o.w = f2bf(v.w);
            ((ushort4*)xb)[i] = o;
        }
        return;
    }
    bid -= CVT_BLKS;

    const float* W; ushort* Wt; int K, N, z, ky, nx;
    if (bid < WT1_TILES) {
        W = Ew1; Wt = W1t; K = IN_; N = EH1_;
        z = bid / (8 * 32); int r = bid % (8 * 32); ky = r / 8; nx = r % 8;
    } else if (bid < WT1_TILES + WT2_TILES) {
        bid -= WT1_TILES;
        W = Ew2; Wt = W2t; K = EH1_; N = EH2_;
        z = bid / (4 * 8); int r = bid % (4 * 8); ky = r / 4; nx = r % 4;
    } else if (bid < WT1_TILES + WT2_TILES + WTG_TILES) {
        bid -= WT1_TILES + WT2_TILES;
        W = Gw1; Wt = G1t; K = IN_; N = GH_;
        z = bid / (2 * 32); int r = bid % (2 * 32); ky = r / 2; nx = r % 2;
    } else {
        // per-chunk count blocks: 256 samples each, LDS counts -> direct write
        int c = bid - (WT1_TILES + WT2_TILES + WTG_TILES);
        if (t < D_) hcnt[t] = 0;
        __syncthreads();
        atomicAdd(&hcnt[dom[c * 256 + t]], 1);
        __syncthreads();
        if (t < D_) cnts[c * D_ + t] = hcnt[t];
        return;
    }
    const int n0 = nx * 32, k0 = ky * 32;
    const float* We = W + (size_t)z * K * N;
    ushort* Wte = Wt + (size_t)z * K * N;
    const int lx = t & 31, ly = t >> 5;
    #pragma unroll
    for (int r = 0; r < 4; ++r)
        tile[ly + r * 8][lx] = We[(size_t)(k0 + ly + r * 8) * N + n0 + lx];
    __syncthreads();
    #pragma unroll
    for (int r = 0; r < 4; ++r)
        Wte[(size_t)(n0 + ly + r * 8) * K + k0 + lx] = f2bf(tile[lx][ly + r * 8]);
}

#define GBK 32
#define H2P 136

// ---------------------------------------------------------------------------
// L1 GEMM (verified 128x128/BK=32 structure). Grid stays exactly (2,128,6)
// = 1536 blocks = residency capacity (6 blocks/CU at <=85 VGPR) -- R5 lesson:
// any extra z-slice creates a 2nd dispatch generation (+27us tail).
// Scatter runs as a PROLOGUE on 64 existing blocks (z==0,x==0,y<64): cnts
// table cached in LDS (coalesced, aliases As), gtab build parallelized.
// ---------------------------------------------------------------------------
__global__ __launch_bounds__(256) void k_gemm(
        const ushort* __restrict__ A, const ushort* __restrict__ Wt,
        const float* __restrict__ Bias, ushort* __restrict__ C,
        const int* __restrict__ dom, const int* __restrict__ cnts,
        int* __restrict__ perm, int* __restrict__ gbaseG,
        int* __restrict__ histG, int* __restrict__ gtab,
        int* __restrict__ ngt) {
    __shared__ __attribute__((aligned(16))) ushort As[128 * GBK];
    __shared__ __attribute__((aligned(16))) ushort Bs[128 * GBK];

    const int t = threadIdx.x;

    if (blockIdx.z == 0 && blockIdx.x == 0 && blockIdx.y < NCHUNK) {
        // ---------- scatter prologue (LDS aliases As; done before staging) --
        int* cl    = (int*)As;              // [NCHUNK*D_] = 1280 ints (5120B)
        int* tot   = cl + NCHUNK * D_;      // [D_]
        int* lbase = tot + D_;              // [D_]
        int* lcnt  = lbase + D_;            // [D_]
        const int c = blockIdx.y;

        for (int i = t; i < NCHUNK * D_; i += 256) cl[i] = cnts[i];
        __syncthreads();
        if (t < D_) {
            int before = 0, total = 0;
            #pragma unroll 8
            for (int cc = 0; cc < NCHUNK; ++cc) {
                int v = cl[cc * D_ + t];
                if (cc < c) before += v;
                total += v;
            }
            tot[t] = total; lbase[t] = before; lcnt[t] = 0;
        }
        __syncthreads();
        if (t < D_) {
            int gb = 0;
            #pragma unroll
            for (int d2 = 0; d2 < D_; ++d2) if (d2 < t) gb += tot[d2];
            lbase[t] += gb;
            if (c == 0) { gbaseG[t] = gb; histG[t] = tot[t]; }
        }
        __syncthreads();
        if (c == 0 && t < D_) {
            // parallel gate-table build: thread t owns domain t's entries
            int off = 0, nt = (tot[t] + 63) >> 6;
            #pragma unroll
            for (int d2 = 0; d2 < D_; ++d2)
                if (d2 < t) off += (tot[d2] + 63) >> 6;
            for (int tt = 0; tt < nt; ++tt) gtab[off + tt] = (t << 16) | tt;
            if (t == D_ - 1) ngt[0] = off + nt;
        }
        {
            const int g = c * 256 + t;
            const int d = dom[g];
            int r = atomicAdd(&lcnt[d], 1);     // LDS-only rank within chunk
            perm[lbase[d] + r] = g;
        }
        __syncthreads();   // As safe to reuse for GEMM staging
    }

    // ---------------- expert L1 GEMM (byte-identical to verified R8) ------
    const int e = blockIdx.z;
    const ushort* Ae = A;
    const ushort* We = Wt + (size_t)e * (size_t)EH1_ * IN_;
    const float* BiasE = Bias + (size_t)e * EH1_;
    ushort* Ce = C + (size_t)e * (size_t)B_ * EH1_;

    const int m0 = blockIdx.y * 128;
    const int n0 = blockIdx.x * 128;
    const int wave = t >> 6;
    const int lane = t & 63;

    const int q0 = wave * 2, q1 = q0 + 1;
    const int sr0 = q0 * 16 + (lane >> 2);
    const int sr1 = sr0 + 16;
    const int sw  = ((lane & 3) ^ ((sr0 >> 1) & 3)) * 8;

    const int l32  = lane & 31;
    const int ksel = lane >> 5;
    const int rw = (wave & 1) * 64;
    const int cw = (wave >> 1) * 64;

    int rowA[2], rowB[2], swzA[2], swzB[2];
    #pragma unroll
    for (int i = 0; i < 2; ++i) {
        rowA[i] = rw + 32 * i + l32;  swzA[i] = (rowA[i] >> 1) & 3;
        rowB[i] = cw + 32 * i + l32;  swzB[i] = (rowB[i] >> 1) & 3;
    }

    f32x16 acc[2][2] = {};

    for (int k0 = 0; k0 < IN_; k0 += GBK) {
        GLOBAL_LDS16(Ae + (size_t)(m0 + sr0) * IN_ + k0 + sw, As + q0 * 512);
        GLOBAL_LDS16(Ae + (size_t)(m0 + sr1) * IN_ + k0 + sw, As + q1 * 512);
        GLOBAL_LDS16(We + (size_t)(n0 + sr0) * IN_ + k0 + sw, Bs + q0 * 512);
        GLOBAL_LDS16(We + (size_t)(n0 + sr1) * IN_ + k0 + sw, Bs + q1 * 512);
        __syncthreads();

        #pragma unroll
        for (int h = 0; h < 2; ++h) {
            const int cb = h * 2 + ksel;
            s16x8 af[2], bf[2];
            #pragma unroll
            for (int i = 0; i < 2; ++i)
                af[i] = *(const s16x8*)&As[rowA[i] * GBK + ((cb ^ swzA[i]) * 8)];
            #pragma unroll
            for (int j = 0; j < 2; ++j)
                bf[j] = *(const s16x8*)&Bs[rowB[j] * GBK + ((cb ^ swzB[j]) * 8)];
            #pragma unroll
            for (int i = 0; i < 2; ++i)
                #pragma unroll
                for (int j = 0; j < 2; ++j)
                    acc[i][j] = __builtin_amdgcn_mfma_f32_32x32x16_bf16(
                        af[i], bf[j], acc[i][j], 0, 0, 0);
        }
        __syncthreads();
    }

    float bi[2];
    #pragma unroll
    for (int j = 0; j < 2; ++j) bi[j] = BiasE[n0 + cw + 32 * j + l32];

    #pragma unroll
    for (int i = 0; i < 2; ++i) {
        #pragma unroll
        for (int reg = 0; reg < 16; ++reg) {
            int rowin = (reg & 3) + 8 * (reg >> 2) + 4 * ksel;
            ushort* crow = Ce + (size_t)(m0 + rw + 32 * i + rowin) * EH1_;
            #pragma unroll
            for (int j = 0; j < 2; ++j) {
                float v = fmaxf(acc[i][j][reg] + bi[j], 0.f);
                crow[n0 + cw + 32 * j + l32] = f2bf(v);
            }
        }
    }
}

#define GYL (E_ + 3)   // 6 l2eo expert slices + 3 gate-table slices

// ---------------------------------------------------------------------------
// Fused expert L2+L3 (verified R8 path) for y<6; gate tiles (dense table)
// for y>=6. Gate overlaps l2eo's 768 blocks instead of tailing the big GEMM.
// ---------------------------------------------------------------------------
__global__ __launch_bounds__(256) void k_l2eog(
        const ushort* __restrict__ h1, const ushort* __restrict__ W2t,
        const float* __restrict__ Eb2, const float* __restrict__ Ew3,
        const float* __restrict__ Eb3, float* __restrict__ eo,
        const ushort* __restrict__ xb, const ushort* __restrict__ Gw1t,
        const float* __restrict__ Gb1, const float* __restrict__ Gw2,
        const float* __restrict__ Gb2, const int* __restrict__ perm,
        const int* __restrict__ histG, const int* __restrict__ gbaseG,
        const int* __restrict__ gtab, const int* __restrict__ ngt,
        float* __restrict__ gate) {
    __shared__ __attribute__((aligned(16))) ushort smem[17408 + 16 * H2P];

    const int t = threadIdx.x;
    const int wave = t >> 6;
    const int lane = t & 63;
    const int quad = lane >> 4;
    const int l16  = lane & 15;
    const int l32  = lane & 31;
    const int ksel = lane >> 5;

    if (blockIdx.y < E_) {
        // ================= L2+L3 branch (verified R8 path) ================
        ushort* As = smem;            // 128*32 elems
        ushort* Bs = smem + 4096;     // 128*32 elems

        const int e = blockIdx.y;
        const ushort* Ae = h1 + (size_t)e * B_ * EH1_;
        const ushort* We = W2t + (size_t)e * EH2_ * EH1_;

        const int m0 = blockIdx.x * 128;

        const int q0 = wave * 2, q1 = q0 + 1;
        const int sr0 = q0 * 16 + (lane >> 2);
        const int sr1 = sr0 + 16;
        const int sw  = ((lane & 3) ^ ((sr0 >> 1) & 3)) * 8;

        const int rw = (wave & 1) * 64;
        const int cw = (wave >> 1) * 64;

        int rowA[2], rowB[2], swzA[2], swzB[2];
        #pragma unroll
        for (int i = 0; i < 2; ++i) {
            rowA[i] = rw + 32 * i + l32;  swzA[i] = (rowA[i] >> 1) & 3;
            rowB[i] = cw + 32 * i + l32;  swzB[i] = (rowB[i] >> 1) & 3;
        }

        f32x16 acc[2][2] = {};

        for (int k0 = 0; k0 < EH1_; k0 += GBK) {
            GLOBAL_LDS16(Ae + (size_t)(m0 + sr0) * EH1_ + k0 + sw, As + q0 * 512);
            GLOBAL_LDS16(Ae + (size_t)(m0 + sr1) * EH1_ + k0 + sw, As + q1 * 512);
            GLOBAL_LDS16(We + (size_t)sr0 * EH1_ + k0 + sw, Bs + q0 * 512);
            GLOBAL_LDS16(We + (size_t)sr1 * EH1_ + k0 + sw, Bs + q1 * 512);
            __syncthreads();

            #pragma unroll
            for (int h = 0; h < 2; ++h) {
                const int cb = h * 2 + ksel;
                s16x8 af[2], bf[2];
                #pragma unroll
                for (int i = 0; i < 2; ++i)
                    af[i] = *(const s16x8*)&As[rowA[i] * GBK + ((cb ^ swzA[i]) * 8)];
                #pragma unroll
                for (int j = 0; j < 2; ++j)
                    bf[j] = *(const s16x8*)&Bs[rowB[j] * GBK + ((cb ^ swzB[j]) * 8)];
                #pragma unroll
                for (int i = 0; i < 2; ++i)
                    #pragma unroll
                    for (int j = 0; j < 2; ++j)
                        acc[i][j] = __builtin_amdgcn_mfma_f32_32x32x16_bf16(
                            af[i], bf[j], acc[i][j], 0, 0, 0);
            }
            __syncthreads();
        }

        // epilogue: h2 tile (bias+relu, bf16) -> LDS, 32x32 C/D scatter
        ushort* h2L = smem;             // [128][H2P]
        ushort* E3t = smem + 128 * H2P; // [16][H2P]

        float bi[2];
        #pragma unroll
        for (int j = 0; j < 2; ++j) bi[j] = Eb2[e * EH2_ + cw + 32 * j + l32];

        #pragma unroll
        for (int i = 0; i < 2; ++i)
            #pragma unroll
            for (int reg = 0; reg < 16; ++reg) {
                int rowin = (reg & 3) + 8 * (reg >> 2) + 4 * ksel;
                int row = rw + 32 * i + rowin;
                #pragma unroll
                for (int j = 0; j < 2; ++j)
                    h2L[row * H2P + cw + 32 * j + l32] =
                        f2bf(fmaxf(acc[i][j][reg] + bi[j], 0.f));
            }

        for (int i = t; i < 16 * 128; i += 256) {
            int col = i >> 7, k = i & 127;
            float v = (col < EO_) ? Ew3[(size_t)e * EH2_ * EO_ + k * EO_ + col] : 0.f;
            E3t[col * H2P + k] = f2bf(v);
        }
        __syncthreads();

        #pragma unroll
        for (int gi = 0; gi < 2; ++gi) {
            int g = wave * 2 + gi;
            f32x4 acc2 = {};
            #pragma unroll
            for (int kc = 0; kc < 4; ++kc) {
                s16x8 a = *(const s16x8*)&h2L[(g * 16 + l16) * H2P + kc * 32 + quad * 8];
                s16x8 b = *(const s16x8*)&E3t[l16 * H2P + kc * 32 + quad * 8];
                acc2 = __builtin_amdgcn_mfma_f32_16x16x32_bf16(a, b, acc2, 0, 0, 0);
            }
            if (l16 < EO_) {
                float b3 = Eb3[e * EO_ + l16];
                #pragma unroll
                for (int r = 0; r < 4; ++r) {
                    int row = m0 + g * 16 + quad * 4 + r;
                    eo[(size_t)row * (E_ * EO_) + e * EO_ + l16] = acc2[r] + b3;
                }
            }
        }
        return;
    }

    // ===================== GATE branch (dense tile table) =================
    {
        const int gidx = (blockIdx.y - E_) * gridDim.x + blockIdx.x;
        if (gidx >= ngt[0]) return;
        const int entry = gtab[gidx];
        const int d     = entry >> 16;
        const int start = (entry & 0xffff) * 64;
        const int base  = gbaseG[d];
        const int cnt   = histG[d];

        // carve gate LDS out of smem (byte offsets; total smem = 39168 B)
        ushort* gAs  = smem;                                   // 4096 B @0
        ushort* gBs  = smem + 2048;                            // 4096 B @4096
        int*    ridx = (int*)(smem + 4096);                    // 256 B  @8192
        float (*gh)[GH_ + 1] = (float(*)[GH_ + 1])(smem + 4224);  // 16640 B @8448
        float*  w2s  = (float*)(smem + 12544);                 // 1536 B @25088
        float*  b2s  = (float*)(smem + 13312);                 // 24 B   @26624
        float (*lg)[E_] = (float(*)[E_])(smem + 13324);        // 1536 B @26648

        const int qsw = (quad ^ ((l16 >> 1) & 3)) * 8;

        if (t < 64) {
            int p = start + t;
            ridx[t] = (p < cnt) ? perm[base + p] : perm[base];  // clamp OOB
        }
        for (int i = t; i < GH_ * E_; i += 256) w2s[i] = Gw2[(size_t)d * GH_ * E_ + i];
        if (t < E_) b2s[t] = Gb2[d * E_ + t];
        __syncthreads();

        const int srow = t >> 2;
        const int sw   = ((t & 3) ^ ((srow >> 1) & 3)) * 8;
        const int myRow = ridx[srow];
        const ushort* aRow = xb + (size_t)myRow * IN_ + sw;
        const ushort* bRow = Gw1t + (size_t)d * GH_ * IN_ + (size_t)srow * IN_ + sw;

        f32x4 acc[4] = {};
        for (int k0 = 0; k0 < IN_; k0 += 32) {
            GLOBAL_LDS16(aRow + k0, gAs + wave * 512);
            GLOBAL_LDS16(bRow + k0, gBs + wave * 512);
            __syncthreads();

            s16x8 bf = *(const s16x8*)&gBs[(wave * 16 + l16) * 32 + qsw];
            #pragma unroll
            for (int i = 0; i < 4; ++i) {
                s16x8 af = *(const s16x8*)&gAs[(16 * i + l16) * 32 + qsw];
                acc[i] = __builtin_amdgcn_mfma_f32_16x16x32_bf16(af, bf, acc[i], 0, 0, 0);
            }
            __syncthreads();
        }

        const int hcol = wave * 16 + l16;
        float hb = Gb1[d * GH_ + hcol];
        #pragma unroll
        for (int i = 0; i < 4; ++i)
            #pragma unroll
            for (int r = 0; r < 4; ++r)
                gh[16 * i + quad * 4 + r][hcol] = fmaxf(acc[i][r] + hb, 0.f);
        __syncthreads();

        for (int p = t; p < 64 * E_; p += 256) {
            int row = p / E_, e = p - row * E_;
            float s = b2s[e];
            #pragma unroll 8
            for (int h = 0; h < GH_; ++h) s += gh[row][h] * w2s[h * E_ + e];
            lg[row][e] = s;
        }
        __syncthreads();

        if (t < 64 && start + t < cnt) {
            int b = ridx[t];
            float mx = lg[t][0];
            #pragma unroll
            for (int e = 1; e < E_; ++e) mx = fmaxf(mx, lg[t][e]);
            float ex[E_], sum = 0.f;
            #pragma unroll
            for (int e = 0; e < E_; ++e) { ex[e] = expf(lg[t][e] - mx); sum += ex[e]; }
            float inv = 1.f / sum;
            #pragma unroll
            for (int e = 0; e < E_; ++e) gate[(size_t)b * E_ + e] = ex[e] * inv;
        }
    }
}

// ---------------------------------------------------------------------------
// Final: MMoE combine + avg + tower, one wave per sample
// ---------------------------------------------------------------------------
__global__ __launch_bounds__(256) void k_final(
        const float* __restrict__ eo, const float* __restrict__ gate,
        const int* __restrict__ dom,
        const float* __restrict__ Tw1, const float* __restrict__ Tb1,
        const float* __restrict__ Tw2, const float* __restrict__ Tb2,
        float* __restrict__ out) {
    const int wave = threadIdx.x >> 6;
    const int lane = threadIdx.x & 63;
    const int b = blockIdx.x * 4 + wave;
    const int d = dom[b];

    const float* eob = eo + (size_t)b * (E_ * EO_);
    float g[E_];
    #pragma unroll
    for (int e = 0; e < E_; ++e) g[e] = gate[(size_t)b * E_ + e];

    float mmoe[EO_], avg[EO_];
    #pragma unroll
    for (int o = 0; o < EO_; ++o) {
        float m = 0.f, a = 0.f;
        #pragma unroll
        for (int e = 0; e < E_; ++e) {
            float v = eob[e * EO_ + o];
            m += g[e] * v;
            a += v;
        }
        mmoe[o] = m;
        avg[o] = a * (1.0f / E_);
    }

    float acc = Tb1[d * TH_ + lane];
    #pragma unroll
    for (int o = 0; o < EO_; ++o)
        acc += mmoe[o] * Tw1[(size_t)d * EO_ * TH_ + o * TH_ + lane];
    acc = fmaxf(acc, 0.f);

    float s = acc * Tw2[d * TH_ + lane];
    #pragma unroll
    for (int off = 32; off >= 1; off >>= 1) s += __shfl_xor(s, off, 64);

    if (lane == 0)
        out[b] = 1.f / (1.f + expf(-(s + Tb2[d])));
    if (lane < EO_) {
        out[B_ + (size_t)b * EO_ + lane] = avg[lane];
        out[B_ + (size_t)B_ * EO_ + (size_t)b * EO_ + lane] = mmoe[lane];
    }
}

// ---------------------------------------------------------------------------
extern "C" void kernel_launch(void* const* d_in, const int* in_sizes, int n_in,
                              void* d_out, int out_size, void* d_ws, size_t ws_size,
                              hipStream_t stream) {
    const float* x   = (const float*)d_in[0];
    const int*   dom = (const int*)d_in[1];
    const float* Ew1 = (const float*)d_in[2];
    const float* Eb1 = (const float*)d_in[3];
    const float* Ew2 = (const float*)d_in[4];
    const float* Eb2 = (const float*)d_in[5];
    const float* Ew3 = (const float*)d_in[6];
    const float* Eb3 = (const float*)d_in[7];
    const float* Gw1 = (const float*)d_in[8];
    const float* Gb1 = (const float*)d_in[9];
    const float* Gw2 = (const float*)d_in[10];
    const float* Gb2 = (const float*)d_in[11];
    const float* Tw1 = (const float*)d_in[12];
    const float* Tb1 = (const float*)d_in[13];
    const float* Tw2 = (const float*)d_in[14];
    const float* Tb2 = (const float*)d_in[15];
    float* out = (float*)d_out;

    char* ws = (char*)d_ws;
    size_t off = 0;
    auto take = [&](size_t bytes) -> char* {
        char* p = ws + off;
        off = (off + bytes + 255) & ~(size_t)255;
        return p;
    };
    int*    cnts    = (int*)take((size_t)NCHUNK * D_ * 4);
    int*    histG   = (int*)take(D_ * 4);
    int*    gbaseG  = (int*)take(D_ * 4);
    int*    gtab    = (int*)take(512 * 4);
    int*    ngt     = (int*)take(4);
    int*    perm    = (int*)take(B_ * 4);
    float*  gateBuf = (float*)take((size_t)B_ * E_ * 4);
    float*  eoBuf   = (float*)take((size_t)B_ * E_ * EO_ * 4);
    ushort* xb      = (ushort*)take((size_t)B_ * IN_ * 2);
    ushort* W1t     = (ushort*)take((size_t)E_ * IN_ * EH1_ * 2);
    ushort* W2t     = (ushort*)take((size_t)E_ * EH1_ * EH2_ * 2);
    ushort* G1t     = (ushort*)take((size_t)D_ * IN_ * GH_ * 2);
    ushort* h1      = (ushort*)take((size_t)E_ * B_ * EH1_ * 2);

    // 1) conversions + transposes + per-chunk counts (no memset needed)
    k_prep<<<dim3(PREP_BLKS), dim3(256), 0, stream>>>(
        x, xb, Ew1, W1t, Ew2, W2t, Gw1, G1t, dom, cnts);

    // 2) L1 GEMM (all experts); scatter as prologue on 64 resident blocks
    k_gemm<<<dim3(EH1_ / 128, B_ / 128, E_), dim3(256), 0, stream>>>(
        xb, W1t, Eb1, h1, dom, cnts, perm, gbaseG, histG, gtab, ngt);

    // 3) fused L2+L3 (y<6) + gates (y>=6, dense table)
    k_l2eog<<<dim3(B_ / 128, GYL), dim3(256), 0, stream>>>(
        h1, W2t, Eb2, Ew3, Eb3, eoBuf,
        xb, G1t, Gb1, Gw2, Gb2, perm, histG, gbaseG, gtab, ngt, gateBuf);

    // 4) combine + towers + outputs
    k_final<<<dim3(B_ / 4), dim3(256), 0, stream>>>(
        eoBuf, gateBuf, dom, Tw1, Tb1, Tw2, Tb2, out);
}